// Round 1
// baseline (894.493 us; speedup 1.0000x reference)
//
#include <hip/hip_runtime.h>

#define B_   8
#define CIN  512
#define NN_  4096
#define DD   256
#define KK   2048

// ---------- kernel 1: e_sq[k] = sum_d emb[k,d]^2 ----------
__global__ __launch_bounds__(256) void k_esq(const float* __restrict__ emb,
                                             float* __restrict__ esq) {
  int t = threadIdx.x;
  int lane = t & 63;
  int k = blockIdx.x * 4 + (t >> 6);
  float4 v = *(const float4*)&emb[(size_t)k * DD + 4 * lane];
  float s = v.x * v.x + v.y * v.y + v.z * v.z + v.w * v.w;
  for (int off = 32; off > 0; off >>= 1) s += __shfl_down(s, off, 64);
  if (lane == 0) esq[k] = s;
}

// ---------- kernel 2: ze[b,d,n] = sum_c W[d,c] * z[b,c,n] ----------
// block tile 128d x 128n, c-chunk 32, per-thread 8x8, register prefetch
__global__ __launch_bounds__(256) void k_ze(const float* __restrict__ W,
                                            const float* __restrict__ z,
                                            float* __restrict__ ze) {
  __shared__ __align__(16) float Ws[32][128];  // [c][d]
  __shared__ __align__(16) float Zs[32][128];  // [c][n]
  const int t = threadIdx.x;
  const int tn = t & 15, tk = t >> 4;
  const int b  = blockIdx.z;
  const int d0 = blockIdx.y * 128;
  const int n0 = blockIdx.x * 128;
  const float* zb = z + (size_t)b * CIN * NN_;

  float acc[8][8];
#pragma unroll
  for (int i = 0; i < 8; i++)
#pragma unroll
    for (int j = 0; j < 8; j++) acc[i][j] = 0.f;

  float4 wA[4], zA[4];
#pragma unroll
  for (int i = 0; i < 4; i++) {  // prefetch chunk 0
    int cid = t + 256 * i;
    int d = cid >> 3, cq = cid & 7;
    wA[i] = *(const float4*)&W[(size_t)(d0 + d) * CIN + 4 * cq];
    int c = cid >> 5, nq = cid & 31;
    zA[i] = *(const float4*)&zb[(size_t)c * NN_ + n0 + 4 * nq];
  }

  for (int c0 = 0; c0 < CIN; c0 += 32) {
    __syncthreads();
#pragma unroll
    for (int i = 0; i < 4; i++) {
      int cid = t + 256 * i;
      int d = cid >> 3, cq = cid & 7;
      float* wp = (float*)&wA[i];
      Ws[4 * cq + 0][d] = wp[0];
      Ws[4 * cq + 1][d] = wp[1];
      Ws[4 * cq + 2][d] = wp[2];
      Ws[4 * cq + 3][d] = wp[3];
      int c = cid >> 5, nq = cid & 31;
      *(float4*)&Zs[c][4 * nq] = zA[i];
    }
    __syncthreads();
    if (c0 + 32 < CIN) {
      int c1 = c0 + 32;
#pragma unroll
      for (int i = 0; i < 4; i++) {
        int cid = t + 256 * i;
        int d = cid >> 3, cq = cid & 7;
        wA[i] = *(const float4*)&W[(size_t)(d0 + d) * CIN + c1 + 4 * cq];
        int c = cid >> 5, nq = cid & 31;
        zA[i] = *(const float4*)&zb[(size_t)(c1 + c) * NN_ + n0 + 4 * nq];
      }
    }
    for (int c = 0; c < 32; c++) {
      float ak[8], an[8];
      *(float4*)&ak[0] = *(const float4*)&Ws[c][4 * tk];
      *(float4*)&ak[4] = *(const float4*)&Ws[c][64 + 4 * tk];
      *(float4*)&an[0] = *(const float4*)&Zs[c][4 * tn];
      *(float4*)&an[4] = *(const float4*)&Zs[c][64 + 4 * tn];
#pragma unroll
      for (int i = 0; i < 8; i++)
#pragma unroll
        for (int j = 0; j < 8; j++) acc[i][j] += ak[i] * an[j];
    }
  }

  float* zeb = ze + (size_t)b * DD * NN_;
#pragma unroll
  for (int i = 0; i < 8; i++) {
    int d = d0 + ((i < 4) ? (4 * tk + i) : (64 + 4 * tk + i - 4));
    float4 v0 = make_float4(acc[i][0], acc[i][1], acc[i][2], acc[i][3]);
    float4 v1 = make_float4(acc[i][4], acc[i][5], acc[i][6], acc[i][7]);
    *(float4*)&zeb[(size_t)d * NN_ + n0 + 4 * tn] = v0;
    *(float4*)&zeb[(size_t)d * NN_ + n0 + 64 + 4 * tn] = v1;
  }
}

// ---------- kernel 3: argmin_k ( esq[k] - 2 * <emb[k], ze[b,:,n]> ) ----------
// block: one (b, 128n) strip; loops 16 k-tiles of 128; d-chunks of 32
__global__ __launch_bounds__(256) void k_argmin(const float* __restrict__ emb,
                                                const float* __restrict__ ze,
                                                const float* __restrict__ esq,
                                                int* __restrict__ min_ind) {
  __shared__ __align__(16) char smem[32 * 128 * 4 + 32 * 128 * 4];  // 32 KB
  float (*Es)[128] = (float(*)[128])smem;                 // [d][k]
  float (*Zs)[128] = (float(*)[128])(smem + 32 * 128 * 4); // [d][n]
  float (*rv)[17] = (float(*)[17])smem;                    // reduction scratch
  int   (*ri)[17] = (int(*)[17])(smem + 128 * 17 * 4);

  const int t = threadIdx.x;
  const int tn = t & 15, tk = t >> 4;
  const int b  = blockIdx.y;
  const int n0 = blockIdx.x * 128;
  const float* zeb = ze + (size_t)b * DD * NN_ + n0;

  float bestv[8];
  int   besti[8];
#pragma unroll
  for (int j = 0; j < 8; j++) { bestv[j] = 3.4e38f; besti[j] = 0; }

  for (int k0 = 0; k0 < KK; k0 += 128) {
    float acc[8][8];
#pragma unroll
    for (int i = 0; i < 8; i++)
#pragma unroll
      for (int j = 0; j < 8; j++) acc[i][j] = 0.f;

    float4 eA[4], zA[4];
#pragma unroll
    for (int i = 0; i < 4; i++) {  // prefetch d-chunk 0
      int cid = t + 256 * i;
      int k = cid >> 3, dq = cid & 7;
      eA[i] = *(const float4*)&emb[(size_t)(k0 + k) * DD + 4 * dq];
      int d = cid >> 5, nq = cid & 31;
      zA[i] = *(const float4*)&zeb[(size_t)d * NN_ + 4 * nq];
    }

    for (int dc = 0; dc < DD; dc += 32) {
      __syncthreads();
#pragma unroll
      for (int i = 0; i < 4; i++) {
        int cid = t + 256 * i;
        int k = cid >> 3, dq = cid & 7;
        float* ep = (float*)&eA[i];
        Es[4 * dq + 0][k] = ep[0];
        Es[4 * dq + 1][k] = ep[1];
        Es[4 * dq + 2][k] = ep[2];
        Es[4 * dq + 3][k] = ep[3];
        int d = cid >> 5, nq = cid & 31;
        *(float4*)&Zs[d][4 * nq] = zA[i];
      }
      __syncthreads();
      if (dc + 32 < DD) {
#pragma unroll
        for (int i = 0; i < 4; i++) {
          int cid = t + 256 * i;
          int k = cid >> 3, dq = cid & 7;
          eA[i] = *(const float4*)&emb[(size_t)(k0 + k) * DD + dc + 32 + 4 * dq];
          int d = cid >> 5, nq = cid & 31;
          zA[i] = *(const float4*)&zeb[(size_t)(dc + 32 + d) * NN_ + 4 * nq];
        }
      }
      for (int d = 0; d < 32; d++) {
        float ak[8], an[8];
        *(float4*)&ak[0] = *(const float4*)&Es[d][4 * tk];
        *(float4*)&ak[4] = *(const float4*)&Es[d][64 + 4 * tk];
        *(float4*)&an[0] = *(const float4*)&Zs[d][4 * tn];
        *(float4*)&an[4] = *(const float4*)&Zs[d][64 + 4 * tn];
#pragma unroll
        for (int i = 0; i < 8; i++)
#pragma unroll
          for (int j = 0; j < 8; j++) acc[i][j] += ak[i] * an[j];
      }
    }
    // fold this k-tile into running argmin (ascending k => first-min tie-break)
#pragma unroll
    for (int i = 0; i < 8; i++) {
      int kl = (i < 4) ? (4 * tk + i) : (64 + 4 * tk + i - 4);
      float es = esq[k0 + kl];
#pragma unroll
      for (int j = 0; j < 8; j++) {
        float d2 = es - 2.0f * acc[i][j];
        if (d2 < bestv[j]) { bestv[j] = d2; besti[j] = k0 + kl; }
      }
    }
  }

  __syncthreads();
#pragma unroll
  for (int j = 0; j < 8; j++) {
    int nl = (j < 4) ? (4 * tn + j) : (64 + 4 * tn + j - 4);
    rv[nl][tk] = bestv[j];
    ri[nl][tk] = besti[j];
  }
  __syncthreads();
  if (t < 128) {
    float bv = rv[t][0];
    int   bi = ri[t][0];
    for (int w = 1; w < 16; w++) {
      float v = rv[t][w];
      int  ii = ri[t][w];
      if (v < bv || (v == bv && ii < bi)) { bv = v; bi = ii; }
    }
    min_ind[(size_t)b * NN_ + n0 + t] = bi;
  }
}

// ---------- kernel 4: gather out = emb[min_ind] ; scatter z_sum / n_sum ----------
__global__ __launch_bounds__(256) void k_gs(const float* __restrict__ emb,
                                            const float* __restrict__ ze,
                                            const int* __restrict__ min_ind,
                                            float* __restrict__ out,
                                            float* __restrict__ z_sum,
                                            float* __restrict__ n_sum) {
  __shared__ __align__(16) char smem[256 * 65 * 4];  // 66560 B
  float (*E)[257] = (float(*)[257])smem;  // 64 x 257 = 65792 B (phase A)
  float (*Z)[65]  = (float(*)[65])smem;   // 256 x 65 = 66560 B (phase B)
  __shared__ int idxl[64];
  const int t = threadIdx.x;
  const int b  = blockIdx.y;
  const int n0 = blockIdx.x * 64;
  if (t < 64) idxl[t] = min_ind[(size_t)b * NN_ + n0 + t];
  __syncthreads();

  // phase A: stage emb rows per local n, then coalesced out writes
  for (int i = 0; i < 16; i++) {
    int cid = t + 256 * i;          // 0..4095
    int r = cid >> 6, q = cid & 63;
    float4 v = *(const float4*)&emb[(size_t)idxl[r] * DD + 4 * q];
    float* vp = (float*)&v;
    E[r][4 * q + 0] = vp[0];
    E[r][4 * q + 1] = vp[1];
    E[r][4 * q + 2] = vp[2];
    E[r][4 * q + 3] = vp[3];
  }
  __syncthreads();
  const int nn = t & 63, dd = t >> 6;
  float* outb = out + (size_t)b * DD * NN_ + n0;
  for (int i = 0; i < 64; i++) {
    int d = 4 * i + dd;
    outb[(size_t)d * NN_ + nn] = E[nn][d];
  }
  __syncthreads();

  // phase B: LDS-transpose ze tile, coalesced atomic scatter
  const float* zeb = ze + (size_t)b * DD * NN_ + n0;
  for (int i = 0; i < 16; i++) {
    int cid = t + 256 * i;
    int d = cid >> 4, q = cid & 15;
    float4 v = *(const float4*)&zeb[(size_t)d * NN_ + 4 * q];
    float* vp = (float*)&v;
    Z[d][4 * q + 0] = vp[0];
    Z[d][4 * q + 1] = vp[1];
    Z[d][4 * q + 2] = vp[2];
    Z[d][4 * q + 3] = vp[3];
  }
  __syncthreads();
  if (t < 64) atomicAdd(&n_sum[idxl[t]], 1.0f);
  for (int n = 0; n < 64; n++) {
    atomicAdd(&z_sum[(size_t)idxl[n] * DD + t], Z[t][n]);
  }
}

// ---------- kernel 5: EMA update ----------
__global__ __launch_bounds__(256) void k_ema(const float* __restrict__ ema_numer,
                                             const float* __restrict__ ema_denom,
                                             const float* __restrict__ z_sum,
                                             const float* __restrict__ n_sum,
                                             float* __restrict__ out_numer,
                                             float* __restrict__ out_denom) {
  const float G  = 0.99f;
  const float OG = 0.009999999776482582f;  // float(1.0 - 0.99) as the reference computes it
  int i = blockIdx.x * 256 + threadIdx.x;
  if (i < KK * DD) {
    out_numer[i] = G * ema_numer[i] + OG * z_sum[i];
  } else {
    int j = i - KK * DD;
    if (j < KK) out_denom[j] = G * ema_denom[j] + OG * n_sum[j];
  }
}

extern "C" void kernel_launch(void* const* d_in, const int* in_sizes, int n_in,
                              void* d_out, int out_size, void* d_ws, size_t ws_size,
                              hipStream_t stream) {
  (void)in_sizes; (void)n_in; (void)out_size; (void)ws_size;
  const float* z         = (const float*)d_in[0];  // (8,512,4096)
  const float* W         = (const float*)d_in[1];  // (256,512)
  const float* emb       = (const float*)d_in[2];  // (2048,256)
  const float* ema_numer = (const float*)d_in[3];  // (2048,256)
  const float* ema_denom = (const float*)d_in[4];  // (2048,)

  float* out       = (float*)d_out;                        // (8,256,4096)
  float* out_numer = out + (size_t)B_ * DD * NN_;          // (2048,256)
  float* out_denom = out_numer + (size_t)KK * DD;          // (2048,)

  float* ws   = (float*)d_ws;
  float* ze   = ws;                                // 8388608 floats
  float* esq  = ze + (size_t)B_ * DD * NN_;        // 2048
  float* nsum = esq + KK;                          // 2048
  float* zsum = nsum + KK;                         // 524288
  int*   mind = (int*)(zsum + (size_t)KK * DD);    // 32768 ints

  // zero the accumulators (ws is poisoned before every timed call)
  hipMemsetAsync(nsum, 0, (size_t)(KK + KK * DD) * sizeof(float), stream);

  k_esq<<<dim3(KK / 4), 256, 0, stream>>>(emb, esq);
  k_ze<<<dim3(NN_ / 128, DD / 128, B_), 256, 0, stream>>>(W, z, ze);
  k_argmin<<<dim3(NN_ / 128, B_), 256, 0, stream>>>(emb, ze, esq, mind);
  k_gs<<<dim3(NN_ / 64, B_), 256, 0, stream>>>(emb, ze, mind, out, zsum, nsum);
  k_ema<<<dim3((KK * DD + KK) / 256), 256, 0, stream>>>(ema_numer, ema_denom, zsum, nsum,
                                                        out_numer, out_denom);
}

// Round 2
// 707.205 us; speedup vs baseline: 1.2648x; 1.2648x over previous
//
#include <hip/hip_runtime.h>

#define B_   8
#define CIN  512
#define NN_  4096
#define DD   256
#define KK   2048
#define KSPLIT 4
#define KPER (KK / KSPLIT)   // 512
#define LP   132             // padded LDS row stride (floats); 528 B, 16B-aligned

// ---------- kernel 1: e_sq[k] = sum_d emb[k,d]^2 ----------
__global__ __launch_bounds__(256) void k_esq(const float* __restrict__ emb,
                                             float* __restrict__ esq) {
  int t = threadIdx.x;
  int lane = t & 63;
  int k = blockIdx.x * 4 + (t >> 6);
  float4 v = *(const float4*)&emb[(size_t)k * DD + 4 * lane];
  float s = v.x * v.x + v.y * v.y + v.z * v.z + v.w * v.w;
  for (int off = 32; off > 0; off >>= 1) s += __shfl_down(s, off, 64);
  if (lane == 0) esq[k] = s;
}

// ---------- kernel 2: ze[b,d,n] = sum_c W[d,c] * z[b,c,n] ----------
// block tile 128d x 128n, c-chunk 32, per-thread 8x8, register prefetch
__global__ __launch_bounds__(256) void k_ze(const float* __restrict__ W,
                                            const float* __restrict__ z,
                                            float* __restrict__ ze) {
  __shared__ __align__(16) float Ws[32][LP];  // [c][d]
  __shared__ __align__(16) float Zs[32][LP];  // [c][n]
  const int t = threadIdx.x;
  const int tn = t & 15, tk = t >> 4;
  const int b  = blockIdx.z;
  const int d0 = blockIdx.y * 128;
  const int n0 = blockIdx.x * 128;
  const float* zb = z + (size_t)b * CIN * NN_;

  float acc[8][8];
#pragma unroll
  for (int i = 0; i < 8; i++)
#pragma unroll
    for (int j = 0; j < 8; j++) acc[i][j] = 0.f;

  float4 wA[4], zA[4];
#pragma unroll
  for (int i = 0; i < 4; i++) {  // prefetch chunk 0
    int cid = t + 256 * i;
    int d = cid >> 3, cq = cid & 7;
    wA[i] = *(const float4*)&W[(size_t)(d0 + d) * CIN + 4 * cq];
    int c = cid >> 5, nq = cid & 31;
    zA[i] = *(const float4*)&zb[(size_t)c * NN_ + n0 + 4 * nq];
  }

  for (int c0 = 0; c0 < CIN; c0 += 32) {
    __syncthreads();
#pragma unroll
    for (int i = 0; i < 4; i++) {
      int cid = t + 256 * i;
      int d = cid >> 3, cq = cid & 7;
      float* wp = (float*)&wA[i];
      Ws[4 * cq + 0][d] = wp[0];
      Ws[4 * cq + 1][d] = wp[1];
      Ws[4 * cq + 2][d] = wp[2];
      Ws[4 * cq + 3][d] = wp[3];
      int c = cid >> 5, nq = cid & 31;
      *(float4*)&Zs[c][4 * nq] = zA[i];
    }
    __syncthreads();
    if (c0 + 32 < CIN) {
      int c1 = c0 + 32;
#pragma unroll
      for (int i = 0; i < 4; i++) {
        int cid = t + 256 * i;
        int d = cid >> 3, cq = cid & 7;
        wA[i] = *(const float4*)&W[(size_t)(d0 + d) * CIN + c1 + 4 * cq];
        int c = cid >> 5, nq = cid & 31;
        zA[i] = *(const float4*)&zb[(size_t)(c1 + c) * NN_ + n0 + 4 * nq];
      }
    }
    for (int c = 0; c < 32; c++) {
      float ak[8], an[8];
      *(float4*)&ak[0] = *(const float4*)&Ws[c][4 * tk];
      *(float4*)&ak[4] = *(const float4*)&Ws[c][64 + 4 * tk];
      *(float4*)&an[0] = *(const float4*)&Zs[c][4 * tn];
      *(float4*)&an[4] = *(const float4*)&Zs[c][64 + 4 * tn];
#pragma unroll
      for (int i = 0; i < 8; i++)
#pragma unroll
        for (int j = 0; j < 8; j++) acc[i][j] += ak[i] * an[j];
    }
  }

  float* zeb = ze + (size_t)b * DD * NN_;
#pragma unroll
  for (int i = 0; i < 8; i++) {
    int d = d0 + ((i < 4) ? (4 * tk + i) : (64 + 4 * tk + i - 4));
    float4 v0 = make_float4(acc[i][0], acc[i][1], acc[i][2], acc[i][3]);
    float4 v1 = make_float4(acc[i][4], acc[i][5], acc[i][6], acc[i][7]);
    *(float4*)&zeb[(size_t)d * NN_ + n0 + 4 * tn] = v0;
    *(float4*)&zeb[(size_t)d * NN_ + n0 + 64 + 4 * tn] = v1;
  }
}

// ---------- kernel 3: partial argmin over one K-split of 512 codes ----------
// grid: (n-strips=32, b=8, ksplit=4); block computes 128n x 512k partial best
__global__ __launch_bounds__(256) void k_argmin(const float* __restrict__ emb,
                                                const float* __restrict__ ze,
                                                const float* __restrict__ esq,
                                                float* __restrict__ pval,
                                                int* __restrict__ pidx) {
  __shared__ __align__(16) char smem[2 * 32 * LP * 4];   // 33792 B
  float (*Es)[LP] = (float(*)[LP])smem;                  // [d][k]
  float (*Zs)[LP] = (float(*)[LP])(smem + 32 * LP * 4);  // [d][n]
  float (*rv)[17] = (float(*)[17])smem;                  // reduction scratch
  int   (*ri)[17] = (int(*)[17])(smem + 128 * 17 * 4);

  const int t = threadIdx.x;
  const int tn = t & 15, tk = t >> 4;
  const int b  = blockIdx.y;
  const int n0 = blockIdx.x * 128;
  const int ks = blockIdx.z;
  const int kbase = ks * KPER;
  const float* zeb = ze + (size_t)b * DD * NN_ + n0;

  float bestv[8];
  int   besti[8];
#pragma unroll
  for (int j = 0; j < 8; j++) { bestv[j] = 3.4e38f; besti[j] = 0; }

  for (int k0 = kbase; k0 < kbase + KPER; k0 += 128) {
    float acc[8][8];
#pragma unroll
    for (int i = 0; i < 8; i++)
#pragma unroll
      for (int j = 0; j < 8; j++) acc[i][j] = 0.f;

    float4 eA[4], zA[4];
#pragma unroll
    for (int i = 0; i < 4; i++) {  // prefetch d-chunk 0
      int cid = t + 256 * i;
      int k = cid >> 3, dq = cid & 7;
      eA[i] = *(const float4*)&emb[(size_t)(k0 + k) * DD + 4 * dq];
      int d = cid >> 5, nq = cid & 31;
      zA[i] = *(const float4*)&zeb[(size_t)d * NN_ + 4 * nq];
    }

    for (int dc = 0; dc < DD; dc += 32) {
      __syncthreads();
#pragma unroll
      for (int i = 0; i < 4; i++) {
        int cid = t + 256 * i;
        int k = cid >> 3, dq = cid & 7;
        float* ep = (float*)&eA[i];
        Es[4 * dq + 0][k] = ep[0];
        Es[4 * dq + 1][k] = ep[1];
        Es[4 * dq + 2][k] = ep[2];
        Es[4 * dq + 3][k] = ep[3];
        int d = cid >> 5, nq = cid & 31;
        *(float4*)&Zs[d][4 * nq] = zA[i];
      }
      __syncthreads();
      if (dc + 32 < DD) {
#pragma unroll
        for (int i = 0; i < 4; i++) {
          int cid = t + 256 * i;
          int k = cid >> 3, dq = cid & 7;
          eA[i] = *(const float4*)&emb[(size_t)(k0 + k) * DD + dc + 32 + 4 * dq];
          int d = cid >> 5, nq = cid & 31;
          zA[i] = *(const float4*)&zeb[(size_t)(dc + 32 + d) * NN_ + 4 * nq];
        }
      }
      for (int d = 0; d < 32; d++) {
        float ak[8], an[8];
        *(float4*)&ak[0] = *(const float4*)&Es[d][4 * tk];
        *(float4*)&ak[4] = *(const float4*)&Es[d][64 + 4 * tk];
        *(float4*)&an[0] = *(const float4*)&Zs[d][4 * tn];
        *(float4*)&an[4] = *(const float4*)&Zs[d][64 + 4 * tn];
#pragma unroll
        for (int i = 0; i < 8; i++)
#pragma unroll
          for (int j = 0; j < 8; j++) acc[i][j] += ak[i] * an[j];
      }
    }
    // fold this k-tile into running argmin (ascending k => first-min tie-break)
#pragma unroll
    for (int i = 0; i < 8; i++) {
      int kl = (i < 4) ? (4 * tk + i) : (64 + 4 * tk + i - 4);
      float es = esq[k0 + kl];
#pragma unroll
      for (int j = 0; j < 8; j++) {
        float d2 = es - 2.0f * acc[i][j];
        if (d2 < bestv[j]) { bestv[j] = d2; besti[j] = k0 + kl; }
      }
    }
  }

  __syncthreads();
#pragma unroll
  for (int j = 0; j < 8; j++) {
    int nl = (j < 4) ? (4 * tn + j) : (64 + 4 * tn + j - 4);
    rv[nl][tk] = bestv[j];
    ri[nl][tk] = besti[j];
  }
  __syncthreads();
  if (t < 128) {
    float bv = rv[t][0];
    int   bi = ri[t][0];
    for (int w = 1; w < 16; w++) {
      float v = rv[t][w];
      int  ii = ri[t][w];
      if (v < bv || (v == bv && ii < bi)) { bv = v; bi = ii; }
    }
    size_t o = ((size_t)ks * B_ + b) * NN_ + n0 + t;
    pval[o] = bv;
    pidx[o] = bi;
  }
}

// ---------- kernel 4: merge partials; gather out = emb[ind]; scatter EMA stats ----------
__global__ __launch_bounds__(256) void k_gs(const float* __restrict__ emb,
                                            const float* __restrict__ ze,
                                            const float* __restrict__ pval,
                                            const int* __restrict__ pidx,
                                            float* __restrict__ out,
                                            float* __restrict__ z_sum,
                                            float* __restrict__ n_sum) {
  __shared__ __align__(16) char smem[256 * 65 * 4];  // 66560 B
  float (*E)[257] = (float(*)[257])smem;  // 64 x 257 (phase A)
  float (*Z)[65]  = (float(*)[65])smem;   // 256 x 65 (phase B)
  __shared__ int idxl[64];
  const int t = threadIdx.x;
  const int b  = blockIdx.y;
  const int n0 = blockIdx.x * 64;

  // merge the KSPLIT partial argmins (ascending ks => ascending k; strict <)
  if (t < 64) {
    size_t base = (size_t)b * NN_ + n0 + t;
    float bv = pval[base];
    int   bi = pidx[base];
#pragma unroll
    for (int ks = 1; ks < KSPLIT; ks++) {
      float v = pval[(size_t)ks * B_ * NN_ + base];
      int  ii = pidx[(size_t)ks * B_ * NN_ + base];
      if (v < bv) { bv = v; bi = ii; }
    }
    idxl[t] = bi;
  }
  __syncthreads();

  // phase A: stage emb rows per local n, then coalesced out writes
  for (int i = 0; i < 16; i++) {
    int cid = t + 256 * i;          // 0..4095
    int r = cid >> 6, q = cid & 63;
    float4 v = *(const float4*)&emb[(size_t)idxl[r] * DD + 4 * q];
    float* vp = (float*)&v;
    E[r][4 * q + 0] = vp[0];
    E[r][4 * q + 1] = vp[1];
    E[r][4 * q + 2] = vp[2];
    E[r][4 * q + 3] = vp[3];
  }
  __syncthreads();
  const int nn = t & 63, dd = t >> 6;
  float* outb = out + (size_t)b * DD * NN_ + n0;
  for (int i = 0; i < 64; i++) {
    int d = 4 * i + dd;
    outb[(size_t)d * NN_ + nn] = E[nn][d];
  }
  __syncthreads();

  // phase B: LDS-transpose ze tile, coalesced atomic scatter
  const float* zeb = ze + (size_t)b * DD * NN_ + n0;
  for (int i = 0; i < 16; i++) {
    int cid = t + 256 * i;
    int d = cid >> 4, q = cid & 15;
    float4 v = *(const float4*)&zeb[(size_t)d * NN_ + 4 * q];
    float* vp = (float*)&v;
    Z[d][4 * q + 0] = vp[0];
    Z[d][4 * q + 1] = vp[1];
    Z[d][4 * q + 2] = vp[2];
    Z[d][4 * q + 3] = vp[3];
  }
  __syncthreads();
  if (t < 64) atomicAdd(&n_sum[idxl[t]], 1.0f);
  for (int n = 0; n < 64; n++) {
    atomicAdd(&z_sum[(size_t)idxl[n] * DD + t], Z[t][n]);
  }
}

// ---------- kernel 5: EMA update ----------
__global__ __launch_bounds__(256) void k_ema(const float* __restrict__ ema_numer,
                                             const float* __restrict__ ema_denom,
                                             const float* __restrict__ z_sum,
                                             const float* __restrict__ n_sum,
                                             float* __restrict__ out_numer,
                                             float* __restrict__ out_denom) {
  const float G  = 0.99f;
  const float OG = 0.009999999776482582f;  // float(1.0 - 0.99)
  int i = blockIdx.x * 256 + threadIdx.x;
  if (i < KK * DD) {
    out_numer[i] = G * ema_numer[i] + OG * z_sum[i];
  } else {
    int j = i - KK * DD;
    if (j < KK) out_denom[j] = G * ema_denom[j] + OG * n_sum[j];
  }
}

extern "C" void kernel_launch(void* const* d_in, const int* in_sizes, int n_in,
                              void* d_out, int out_size, void* d_ws, size_t ws_size,
                              hipStream_t stream) {
  (void)in_sizes; (void)n_in; (void)out_size; (void)ws_size;
  const float* z         = (const float*)d_in[0];  // (8,512,4096)
  const float* W         = (const float*)d_in[1];  // (256,512)
  const float* emb       = (const float*)d_in[2];  // (2048,256)
  const float* ema_numer = (const float*)d_in[3];  // (2048,256)
  const float* ema_denom = (const float*)d_in[4];  // (2048,)

  float* out       = (float*)d_out;                        // (8,256,4096)
  float* out_numer = out + (size_t)B_ * DD * NN_;          // (2048,256)
  float* out_denom = out_numer + (size_t)KK * DD;          // (2048,)

  float* ws   = (float*)d_ws;
  float* ze   = ws;                                 // 8388608 floats
  float* esq  = ze + (size_t)B_ * DD * NN_;         // 2048
  float* nsum = esq + KK;                           // 2048
  float* zsum = nsum + KK;                          // 524288
  float* pval = zsum + (size_t)KK * DD;             // 131072
  int*   pidx = (int*)(pval + (size_t)KSPLIT * B_ * NN_);  // 131072 ints

  // zero the accumulators (ws is poisoned before every timed call)
  hipMemsetAsync(nsum, 0, (size_t)(KK + KK * DD) * sizeof(float), stream);

  k_esq<<<dim3(KK / 4), 256, 0, stream>>>(emb, esq);
  k_ze<<<dim3(NN_ / 128, DD / 128, B_), 256, 0, stream>>>(W, z, ze);
  k_argmin<<<dim3(NN_ / 128, B_, KSPLIT), 256, 0, stream>>>(emb, ze, esq, pval, pidx);
  k_gs<<<dim3(NN_ / 64, B_), 256, 0, stream>>>(emb, ze, pval, pidx, out, zsum, nsum);
  k_ema<<<dim3((KK * DD + KK) / 256), 256, 0, stream>>>(ema_numer, ema_denom, zsum, nsum,
                                                        out_numer, out_denom);
}

// Round 3
// 384.708 us; speedup vs baseline: 2.3251x; 1.8383x over previous
//
#include <hip/hip_runtime.h>

#define B_   8
#define CIN  512
#define NN_  4096
#define DD   256
#define KK   2048
#define KSPLIT 4
#define KPER (KK / KSPLIT)   // 512
#define LP   132             // padded LDS row stride for k_ze (floats)

typedef _Float16 f16x8 __attribute__((ext_vector_type(8)));
typedef _Float16 f16x4 __attribute__((ext_vector_type(4)));
typedef float    f32x16 __attribute__((ext_vector_type(16)));

#define MFMA16 __builtin_amdgcn_mfma_f32_32x32x16_f16

// async global->LDS, 16B per lane; LDS dest is wave-uniform base + lane*16
#define GLDS16(gp, lp) __builtin_amdgcn_global_load_lds( \
    (const __attribute__((address_space(1))) void*)(gp), \
    (__attribute__((address_space(3))) void*)(lp), 16, 0, 0)

// ---------- kernel 1: esq[k] = sum_d emb[k,d]^2 ; emit emb hi/lo f16 ----------
__global__ __launch_bounds__(256) void k_esq(const float* __restrict__ emb,
                                             float* __restrict__ esq,
                                             _Float16* __restrict__ emb_h,
                                             _Float16* __restrict__ emb_l) {
  int t = threadIdx.x;
  int lane = t & 63;
  int k = blockIdx.x * 4 + (t >> 6);
  float4 v = *(const float4*)&emb[(size_t)k * DD + 4 * lane];
  float s = v.x * v.x + v.y * v.y + v.z * v.z + v.w * v.w;
  f16x4 h, l;
  float* vp = (float*)&v;
#pragma unroll
  for (int i = 0; i < 4; i++) {
    _Float16 hh = (_Float16)vp[i];
    h[i] = hh;
    l[i] = (_Float16)(vp[i] - (float)hh);
  }
  *(f16x4*)&emb_h[(size_t)k * DD + 4 * lane] = h;
  *(f16x4*)&emb_l[(size_t)k * DD + 4 * lane] = l;
  for (int off = 32; off > 0; off >>= 1) s += __shfl_down(s, off, 64);
  if (lane == 0) esq[k] = s;
}

// ---------- kernel 2: ze[b,d,n] = sum_c W[d,c] * z[b,c,n] (fp32 VALU GEMM) ----------
__global__ __launch_bounds__(256) void k_ze(const float* __restrict__ W,
                                            const float* __restrict__ z,
                                            float* __restrict__ ze) {
  __shared__ __align__(16) float Ws[32][LP];
  __shared__ __align__(16) float Zs[32][LP];
  const int t = threadIdx.x;
  const int tn = t & 15, tk = t >> 4;
  const int b  = blockIdx.z;
  const int d0 = blockIdx.y * 128;
  const int n0 = blockIdx.x * 128;
  const float* zb = z + (size_t)b * CIN * NN_;

  float acc[8][8];
#pragma unroll
  for (int i = 0; i < 8; i++)
#pragma unroll
    for (int j = 0; j < 8; j++) acc[i][j] = 0.f;

  float4 wA[4], zA[4];
#pragma unroll
  for (int i = 0; i < 4; i++) {
    int cid = t + 256 * i;
    int d = cid >> 3, cq = cid & 7;
    wA[i] = *(const float4*)&W[(size_t)(d0 + d) * CIN + 4 * cq];
    int c = cid >> 5, nq = cid & 31;
    zA[i] = *(const float4*)&zb[(size_t)c * NN_ + n0 + 4 * nq];
  }

  for (int c0 = 0; c0 < CIN; c0 += 32) {
    __syncthreads();
#pragma unroll
    for (int i = 0; i < 4; i++) {
      int cid = t + 256 * i;
      int d = cid >> 3, cq = cid & 7;
      float* wp = (float*)&wA[i];
      Ws[4 * cq + 0][d] = wp[0];
      Ws[4 * cq + 1][d] = wp[1];
      Ws[4 * cq + 2][d] = wp[2];
      Ws[4 * cq + 3][d] = wp[3];
      int c = cid >> 5, nq = cid & 31;
      *(float4*)&Zs[c][4 * nq] = zA[i];
    }
    __syncthreads();
    if (c0 + 32 < CIN) {
      int c1 = c0 + 32;
#pragma unroll
      for (int i = 0; i < 4; i++) {
        int cid = t + 256 * i;
        int d = cid >> 3, cq = cid & 7;
        wA[i] = *(const float4*)&W[(size_t)(d0 + d) * CIN + c1 + 4 * cq];
        int c = cid >> 5, nq = cid & 31;
        zA[i] = *(const float4*)&zb[(size_t)(c1 + c) * NN_ + n0 + 4 * nq];
      }
    }
    for (int c = 0; c < 32; c++) {
      float ak[8], an[8];
      *(float4*)&ak[0] = *(const float4*)&Ws[c][4 * tk];
      *(float4*)&ak[4] = *(const float4*)&Ws[c][64 + 4 * tk];
      *(float4*)&an[0] = *(const float4*)&Zs[c][4 * tn];
      *(float4*)&an[4] = *(const float4*)&Zs[c][64 + 4 * tn];
#pragma unroll
      for (int i = 0; i < 8; i++)
#pragma unroll
        for (int j = 0; j < 8; j++) acc[i][j] += ak[i] * an[j];
    }
  }

  float* zeb = ze + (size_t)b * DD * NN_;
#pragma unroll
  for (int i = 0; i < 8; i++) {
    int d = d0 + ((i < 4) ? (4 * tk + i) : (64 + 4 * tk + i - 4));
    float4 v0 = make_float4(acc[i][0], acc[i][1], acc[i][2], acc[i][3]);
    float4 v1 = make_float4(acc[i][4], acc[i][5], acc[i][6], acc[i][7]);
    *(float4*)&zeb[(size_t)d * NN_ + n0 + 4 * tn] = v0;
    *(float4*)&zeb[(size_t)d * NN_ + n0 + 64 + 4 * tn] = v1;
  }
}

// ---------- kernel 2b: transpose+split ze[d][n] fp32 -> zeT[n][d] hi/lo f16 ----------
__global__ __launch_bounds__(256) void k_split(const float* __restrict__ ze,
                                               _Float16* __restrict__ zeT_h,
                                               _Float16* __restrict__ zeT_l) {
  __shared__ float T[64][69];
  const int t = threadIdx.x;
  const int b = blockIdx.z, d0 = blockIdx.y * 64, n0 = blockIdx.x * 64;
  const float* zb = ze + ((size_t)b * DD + d0) * NN_ + n0;
#pragma unroll
  for (int p = 0; p < 4; p++) {
    int dl = p * 16 + (t >> 4);
    float4 v = *(const float4*)&zb[(size_t)dl * NN_ + 4 * (t & 15)];
    T[dl][4 * (t & 15) + 0] = v.x;
    T[dl][4 * (t & 15) + 1] = v.y;
    T[dl][4 * (t & 15) + 2] = v.z;
    T[dl][4 * (t & 15) + 3] = v.w;
  }
  __syncthreads();
#pragma unroll
  for (int p = 0; p < 4; p++) {
    int nl = p * 16 + (t >> 4);
    int dq = (t & 15) * 4;
    f16x4 h, l;
#pragma unroll
    for (int i = 0; i < 4; i++) {
      float x = T[dq + i][nl];
      _Float16 hh = (_Float16)x;
      h[i] = hh;
      l[i] = (_Float16)(x - (float)hh);
    }
    size_t o = ((size_t)b * NN_ + n0 + nl) * DD + d0 + dq;
    *(f16x4*)&zeT_h[o] = h;
    *(f16x4*)&zeT_l[o] = l;
  }
}

// ---------- kernel 3: MFMA split-f16 partial argmin over one K-split ----------
// d2 = esq[k] - 2*cross; cross via 3 MFMA passes (hh, hl, lh)
__global__ __launch_bounds__(256) void k_argmin(const _Float16* __restrict__ emb_h,
                                                const _Float16* __restrict__ emb_l,
                                                const _Float16* __restrict__ zeT_h,
                                                const _Float16* __restrict__ zeT_l,
                                                const float* __restrict__ esq,
                                                float* __restrict__ pval,
                                                int* __restrict__ pidx) {
  // EH[2][128][32] @0, EL @16384, ZH @32768, ZL @49152 (f16; 64B rows)
  // esqs(512 f32) @65536, pv @67584, pi @68608
  __shared__ __align__(16) char sm[69632];
  const int t = threadIdx.x;
  const int w = t >> 6, lane = t & 63;
  const int lr = lane & 31, lh = lane >> 5;
  const int wm = w & 1, wn = w >> 1;
  const int b = blockIdx.y, n0 = blockIdx.x * 128, ks = blockIdx.z;
  const int kbase = ks * KPER;

  float* esqs = (float*)(sm + 65536);
  *(float2*)&esqs[2 * t] = *(const float2*)&esq[kbase + 2 * t];

  const _Float16* zb_h = zeT_h + ((size_t)b * NN_ + n0) * DD;
  const _Float16* zb_l = zeT_l + ((size_t)b * NN_ + n0) * DD;

  auto stage = [&](int buf, int kt, int dc) {
    const int k0 = kbase + kt * 128;
    const int q = lane & 3, rr = lane >> 2;
    const int rb0 = 32 * w;
#pragma unroll
    for (int j = 0; j < 2; j++) {
      int rb = rb0 + 16 * j;
      int r = rb + rr;
      int col = dc + 8 * q;
      size_t eo = (size_t)(k0 + r) * DD + col;
      size_t zo = (size_t)r * DD + col;
      char* lb = sm + (size_t)buf * 8192 + rb * 64;
      GLDS16(emb_h + eo, lb);
      GLDS16(emb_l + eo, lb + 16384);
      GLDS16(zb_h + zo, lb + 32768);
      GLDS16(zb_l + zo, lb + 49152);
    }
  };

  f32x16 vzero;
#pragma unroll
  for (int i = 0; i < 16; i++) vzero[i] = 0.0f;

  float bestv[2];
  int   besti[2];
  bestv[0] = bestv[1] = 3.4e38f;
  besti[0] = besti[1] = 0;

  stage(0, 0, 0);
  int buf = 0;
  for (int kt = 0; kt < 4; kt++) {
    f32x16 acc00 = vzero, acc01 = vzero, acc10 = vzero, acc11 = vzero;
    for (int dc = 0; dc < DD; dc += 32) {
      __syncthreads();
      if (dc + 32 < DD) stage(buf ^ 1, kt, dc + 32);
      else if (kt < 3) stage(buf ^ 1, kt + 1, 0);
      const _Float16* EHb = (const _Float16*)(sm + buf * 8192);
      const _Float16* ELb = (const _Float16*)(sm + 16384 + buf * 8192);
      const _Float16* ZHb = (const _Float16*)(sm + 32768 + buf * 8192);
      const _Float16* ZLb = (const _Float16*)(sm + 49152 + buf * 8192);
#pragma unroll
      for (int s = 0; s < 2; s++) {
        const int acol = s * 16 + lh * 8;
        const int ar0 = (wm * 64 + lr) * 32 + acol;
        const int ar1 = (wm * 64 + 32 + lr) * 32 + acol;
        const int br0 = (wn * 64 + lr) * 32 + acol;
        const int br1 = (wn * 64 + 32 + lr) * 32 + acol;
        f16x8 ah0 = *(const f16x8*)(EHb + ar0);
        f16x8 ah1 = *(const f16x8*)(EHb + ar1);
        f16x8 al0 = *(const f16x8*)(ELb + ar0);
        f16x8 al1 = *(const f16x8*)(ELb + ar1);
        f16x8 bh0 = *(const f16x8*)(ZHb + br0);
        f16x8 bh1 = *(const f16x8*)(ZHb + br1);
        f16x8 bl0 = *(const f16x8*)(ZLb + br0);
        f16x8 bl1 = *(const f16x8*)(ZLb + br1);
        acc00 = MFMA16(ah0, bh0, acc00, 0, 0, 0);
        acc01 = MFMA16(ah0, bh1, acc01, 0, 0, 0);
        acc10 = MFMA16(ah1, bh0, acc10, 0, 0, 0);
        acc11 = MFMA16(ah1, bh1, acc11, 0, 0, 0);
        acc00 = MFMA16(ah0, bl0, acc00, 0, 0, 0);
        acc01 = MFMA16(ah0, bl1, acc01, 0, 0, 0);
        acc10 = MFMA16(ah1, bl0, acc10, 0, 0, 0);
        acc11 = MFMA16(ah1, bl1, acc11, 0, 0, 0);
        acc00 = MFMA16(al0, bh0, acc00, 0, 0, 0);
        acc01 = MFMA16(al0, bh1, acc01, 0, 0, 0);
        acc10 = MFMA16(al1, bh0, acc10, 0, 0, 0);
        acc11 = MFMA16(al1, bh1, acc11, 0, 0, 0);
      }
      buf ^= 1;
    }
    // fold: C layout col=lane&31, row=(r&3)+8*(r>>2)+4*(lane>>5)
#pragma unroll
    for (int mt = 0; mt < 2; mt++)
#pragma unroll
      for (int nt = 0; nt < 2; nt++) {
        const f32x16& a = (mt == 0) ? (nt == 0 ? acc00 : acc01)
                                    : (nt == 0 ? acc10 : acc11);
#pragma unroll
        for (int r = 0; r < 16; r++) {
          int kl = kt * 128 + wm * 64 + mt * 32 + (r & 3) + 8 * (r >> 2) + 4 * lh;
          float d2 = esqs[kl] - 2.0f * a[r];
          int kg = kbase + kl;
          if (d2 < bestv[nt] || (d2 == bestv[nt] && kg < besti[nt])) {
            bestv[nt] = d2; besti[nt] = kg;
          }
        }
      }
  }

  // merge lane pairs (lane ^ 32 shares the same n column)
#pragma unroll
  for (int nt = 0; nt < 2; nt++) {
    float ov = __shfl_xor(bestv[nt], 32, 64);
    int   oi = __shfl_xor(besti[nt], 32, 64);
    if (ov < bestv[nt] || (ov == bestv[nt] && oi < besti[nt])) {
      bestv[nt] = ov; besti[nt] = oi;
    }
  }
  float* pv = (float*)(sm + 67584);
  int*   pi = (int*)(sm + 68608);
  __syncthreads();
  if (lh == 0) {
#pragma unroll
    for (int nt = 0; nt < 2; nt++) {
      pv[(w * 2 + nt) * 32 + lr] = bestv[nt];
      pi[(w * 2 + nt) * 32 + lr] = besti[nt];
    }
  }
  __syncthreads();
  if (t < 128) {
    int wn2 = t >> 6, nt = (t >> 5) & 1, nl = t & 31;
    int i0 = ((2 * wn2 + 0) * 2 + nt) * 32 + nl;
    int i1 = ((2 * wn2 + 1) * 2 + nt) * 32 + nl;
    float v0 = pv[i0], v1 = pv[i1];
    int   j0 = pi[i0], j1 = pi[i1];
    if (v1 < v0 || (v1 == v0 && j1 < j0)) { v0 = v1; j0 = j1; }
    size_t o = ((size_t)ks * B_ + b) * NN_ + n0 + t;
    pval[o] = v0;
    pidx[o] = j0;
  }
}

// ---------- kernel 4: merge partials; gather out = emb[ind]; scatter EMA stats ----------
__global__ __launch_bounds__(256) void k_gs(const float* __restrict__ emb,
                                            const float* __restrict__ ze,
                                            const float* __restrict__ pval,
                                            const int* __restrict__ pidx,
                                            float* __restrict__ out,
                                            float* __restrict__ z_sum,
                                            float* __restrict__ n_sum) {
  __shared__ __align__(16) char smem[256 * 65 * 4];
  float (*E)[257] = (float(*)[257])smem;
  float (*Z)[65]  = (float(*)[65])smem;
  __shared__ int idxl[64];
  const int t = threadIdx.x;
  const int b  = blockIdx.y;
  const int n0 = blockIdx.x * 64;

  if (t < 64) {
    size_t base = (size_t)b * NN_ + n0 + t;
    float bv = pval[base];
    int   bi = pidx[base];
#pragma unroll
    for (int ks = 1; ks < KSPLIT; ks++) {
      float v = pval[(size_t)ks * B_ * NN_ + base];
      int  ii = pidx[(size_t)ks * B_ * NN_ + base];
      if (v < bv || (v == bv && ii < bi)) { bv = v; bi = ii; }
    }
    idxl[t] = bi;
  }
  __syncthreads();

  for (int i = 0; i < 16; i++) {
    int cid = t + 256 * i;
    int r = cid >> 6, q = cid & 63;
    float4 v = *(const float4*)&emb[(size_t)idxl[r] * DD + 4 * q];
    float* vp = (float*)&v;
    E[r][4 * q + 0] = vp[0];
    E[r][4 * q + 1] = vp[1];
    E[r][4 * q + 2] = vp[2];
    E[r][4 * q + 3] = vp[3];
  }
  __syncthreads();
  const int nn = t & 63, dd = t >> 6;
  float* outb = out + (size_t)b * DD * NN_ + n0;
  for (int i = 0; i < 64; i++) {
    int d = 4 * i + dd;
    outb[(size_t)d * NN_ + nn] = E[nn][d];
  }
  __syncthreads();

  const float* zeb = ze + (size_t)b * DD * NN_ + n0;
  for (int i = 0; i < 16; i++) {
    int cid = t + 256 * i;
    int d = cid >> 4, q = cid & 15;
    float4 v = *(const float4*)&zeb[(size_t)d * NN_ + 4 * q];
    float* vp = (float*)&v;
    Z[d][4 * q + 0] = vp[0];
    Z[d][4 * q + 1] = vp[1];
    Z[d][4 * q + 2] = vp[2];
    Z[d][4 * q + 3] = vp[3];
  }
  __syncthreads();
  if (t < 64) atomicAdd(&n_sum[idxl[t]], 1.0f);
  for (int n = 0; n < 64; n++) {
    atomicAdd(&z_sum[(size_t)idxl[n] * DD + t], Z[t][n]);
  }
}

// ---------- kernel 5: EMA update ----------
__global__ __launch_bounds__(256) void k_ema(const float* __restrict__ ema_numer,
                                             const float* __restrict__ ema_denom,
                                             const float* __restrict__ z_sum,
                                             const float* __restrict__ n_sum,
                                             float* __restrict__ out_numer,
                                             float* __restrict__ out_denom) {
  const float G  = 0.99f;
  const float OG = 0.009999999776482582f;
  int i = blockIdx.x * 256 + threadIdx.x;
  if (i < KK * DD) {
    out_numer[i] = G * ema_numer[i] + OG * z_sum[i];
  } else {
    int j = i - KK * DD;
    if (j < KK) out_denom[j] = G * ema_denom[j] + OG * n_sum[j];
  }
}

extern "C" void kernel_launch(void* const* d_in, const int* in_sizes, int n_in,
                              void* d_out, int out_size, void* d_ws, size_t ws_size,
                              hipStream_t stream) {
  (void)in_sizes; (void)n_in; (void)out_size; (void)ws_size;
  const float* z         = (const float*)d_in[0];
  const float* W         = (const float*)d_in[1];
  const float* emb       = (const float*)d_in[2];
  const float* ema_numer = (const float*)d_in[3];
  const float* ema_denom = (const float*)d_in[4];

  float* out       = (float*)d_out;                        // (8,256,4096)
  float* out_numer = out + (size_t)B_ * DD * NN_;
  float* out_denom = out_numer + (size_t)KK * DD;

  float* ws   = (float*)d_ws;
  float* ze   = ws;                                        // 8M floats (32 MB)
  float* esq  = ze + (size_t)B_ * DD * NN_;                // 2048
  float* nsum = esq + KK;                                  // 2048
  float* zsum = nsum + KK;                                 // 524288
  float* pval = zsum + (size_t)KK * DD;                    // 131072
  int*   pidx = (int*)(pval + (size_t)KSPLIT * B_ * NN_);  // 131072
  _Float16* emb_h = (_Float16*)(pidx + (size_t)KSPLIT * B_ * NN_);  // 512K f16
  _Float16* emb_l = emb_h + (size_t)KK * DD;                        // 512K f16

  // zeT hi/lo (16 MB each) live in d_out scratch: k_argmin finishes before
  // k_gs/k_ema write the real outputs (same stream serializes).
  _Float16* zeT_h = (_Float16*)d_out;
  _Float16* zeT_l = zeT_h + (size_t)B_ * NN_ * DD;

  hipMemsetAsync(nsum, 0, (size_t)(KK + KK * DD) * sizeof(float), stream);

  k_esq<<<dim3(KK / 4), 256, 0, stream>>>(emb, esq, emb_h, emb_l);
  k_ze<<<dim3(NN_ / 128, DD / 128, B_), 256, 0, stream>>>(W, z, ze);
  k_split<<<dim3(NN_ / 64, DD / 64, B_), 256, 0, stream>>>(ze, zeT_h, zeT_l);
  k_argmin<<<dim3(NN_ / 128, B_, KSPLIT), 256, 0, stream>>>(emb_h, emb_l, zeT_h, zeT_l,
                                                            esq, pval, pidx);
  k_gs<<<dim3(NN_ / 64, B_), 256, 0, stream>>>(emb, ze, pval, pidx, out, zsum, nsum);
  k_ema<<<dim3((KK * DD + KK) / 256), 256, 0, stream>>>(ema_numer, ema_denom, zsum, nsum,
                                                        out_numer, out_denom);
}

// Round 4
// 380.400 us; speedup vs baseline: 2.3515x; 1.0113x over previous
//
#include <hip/hip_runtime.h>

#define B_   8
#define CIN  512
#define NN_  4096
#define DD   256
#define KK   2048
#define KSPLIT 4
#define KPER (KK / KSPLIT)   // 512

typedef _Float16 f16x8 __attribute__((ext_vector_type(8)));
typedef _Float16 f16x4 __attribute__((ext_vector_type(4)));
typedef float    f32x16 __attribute__((ext_vector_type(16)));

#define MFMA16 __builtin_amdgcn_mfma_f32_32x32x16_f16

// async global->LDS, 16B per lane; LDS dest is wave-uniform base + lane*16
#define GLDS16(gp, lp) __builtin_amdgcn_global_load_lds( \
    (const __attribute__((address_space(1))) void*)(gp), \
    (__attribute__((address_space(3))) void*)(lp), 16, 0, 0)

// ---------- kernel 1: esq[k] = sum_d emb[k,d]^2 ; emit emb hi/lo f16 ----------
__global__ __launch_bounds__(256) void k_esq(const float* __restrict__ emb,
                                             float* __restrict__ esq,
                                             _Float16* __restrict__ emb_h,
                                             _Float16* __restrict__ emb_l) {
  int t = threadIdx.x;
  int lane = t & 63;
  int k = blockIdx.x * 4 + (t >> 6);
  float4 v = *(const float4*)&emb[(size_t)k * DD + 4 * lane];
  float s = v.x * v.x + v.y * v.y + v.z * v.z + v.w * v.w;
  f16x4 h, l;
  float* vp = (float*)&v;
#pragma unroll
  for (int i = 0; i < 4; i++) {
    _Float16 hh = (_Float16)vp[i];
    h[i] = hh;
    l[i] = (_Float16)(vp[i] - (float)hh);
  }
  *(f16x4*)&emb_h[(size_t)k * DD + 4 * lane] = h;
  *(f16x4*)&emb_l[(size_t)k * DD + 4 * lane] = l;
  for (int off = 32; off > 0; off >>= 1) s += __shfl_down(s, off, 64);
  if (lane == 0) esq[k] = s;
}

// ---------- kernel 2: MFMA split-f16 conv: zeT_{h,l}[b,n,d] = sum_c W[d,c] z[b,c,n] ----------
// block tile 128d x 128n, c-chunks of 32 double-buffered; epilogue emits
// transposed hi/lo f16 directly (no fp32 ze array at all).
__global__ __launch_bounds__(256) void k_ze(const float* __restrict__ W,
                                            const float* __restrict__ z,
                                            _Float16* __restrict__ zeT_h,
                                            _Float16* __restrict__ zeT_l) {
  // Ah[2][128][40] f16 @0 (20480), Al @20480 (20480), Zs[2][32][128] f32 @40960 (32768)
  // epilogue overlay: Eh[128][132] f16 @0 (33792), El @33792
  __shared__ __align__(16) char sm[73728];
  const int t = threadIdx.x;
  const int w = t >> 6, lane = t & 63;
  const int lr = lane & 31, lh = lane >> 5;
  const int wm = w & 1, wn = w >> 1;
  const int b = blockIdx.z, d0 = blockIdx.y * 128, n0 = blockIdx.x * 128;
  const float* zb = z + (size_t)b * CIN * NN_ + n0;

  _Float16* Ah = (_Float16*)sm;             // [2][128][40]
  _Float16* Al = (_Float16*)(sm + 20480);   // [2][128][40]
  float*    Zs = (float*)(sm + 40960);      // [2][32][128]

  auto stageA = [&](int buf, int c0) {
#pragma unroll
    for (int i = 0; i < 4; i++) {
      int fid = i * 256 + t;           // 0..1023
      int d = fid >> 3, q = fid & 7;   // 128 rows x 8 c-quads
      float4 v = *(const float4*)&W[(size_t)(d0 + d) * CIN + c0 + 4 * q];
      float* vp = (float*)&v;
      f16x4 h, l;
#pragma unroll
      for (int e = 0; e < 4; e++) {
        _Float16 hh = (_Float16)vp[e];
        h[e] = hh;
        l[e] = (_Float16)(vp[e] - (float)hh);
      }
      *(f16x4*)&Ah[(size_t)(buf * 128 + d) * 40 + 4 * q] = h;
      *(f16x4*)&Al[(size_t)(buf * 128 + d) * 40 + 4 * q] = l;
    }
  };
  auto stageZ = [&](int buf, int c0) {
#pragma unroll
    for (int i = 0; i < 4; i++) {
      int r = 8 * w + 2 * i;           // row pair handled by this instr
      float* lbase = Zs + (size_t)buf * 4096 + r * 128;
      const float* gp = zb + (size_t)(c0 + r + lh) * NN_ + 4 * lr;
      GLDS16(gp, lbase);
    }
  };

  f32x16 acc[2][2];
#pragma unroll
  for (int mt = 0; mt < 2; mt++)
#pragma unroll
    for (int nt = 0; nt < 2; nt++)
#pragma unroll
      for (int i = 0; i < 16; i++) acc[mt][nt][i] = 0.0f;

  stageA(0, 0);
  stageZ(0, 0);
  int buf = 0;
  for (int c0 = 0; c0 < CIN; c0 += 32) {
    __syncthreads();
    if (c0 + 32 < CIN) { stageA(buf ^ 1, c0 + 32); stageZ(buf ^ 1, c0 + 32); }
    const _Float16* AhB = Ah + (size_t)buf * 128 * 40;
    const _Float16* AlB = Al + (size_t)buf * 128 * 40;
    const float*    ZsB = Zs + (size_t)buf * 4096;
#pragma unroll
    for (int s = 0; s < 2; s++) {
      const int ca = 16 * s + 8 * lh;
      f16x8 ah0 = *(const f16x8*)&AhB[(wm * 64 + lr) * 40 + ca];
      f16x8 ah1 = *(const f16x8*)&AhB[(wm * 64 + 32 + lr) * 40 + ca];
      f16x8 al0 = *(const f16x8*)&AlB[(wm * 64 + lr) * 40 + ca];
      f16x8 al1 = *(const f16x8*)&AlB[(wm * 64 + 32 + lr) * 40 + ca];
      f16x8 bh0, bl0, bh1, bl1;
#pragma unroll
      for (int j = 0; j < 8; j++) {
        float x0 = ZsB[(ca + j) * 128 + wn * 64 + lr];
        float x1 = ZsB[(ca + j) * 128 + wn * 64 + 32 + lr];
        _Float16 h0 = (_Float16)x0;
        bh0[j] = h0;
        bl0[j] = (_Float16)(x0 - (float)h0);
        _Float16 h1 = (_Float16)x1;
        bh1[j] = h1;
        bl1[j] = (_Float16)(x1 - (float)h1);
      }
      acc[0][0] = MFMA16(ah0, bh0, acc[0][0], 0, 0, 0);
      acc[0][1] = MFMA16(ah0, bh1, acc[0][1], 0, 0, 0);
      acc[1][0] = MFMA16(ah1, bh0, acc[1][0], 0, 0, 0);
      acc[1][1] = MFMA16(ah1, bh1, acc[1][1], 0, 0, 0);
      acc[0][0] = MFMA16(ah0, bl0, acc[0][0], 0, 0, 0);
      acc[0][1] = MFMA16(ah0, bl1, acc[0][1], 0, 0, 0);
      acc[1][0] = MFMA16(ah1, bl0, acc[1][0], 0, 0, 0);
      acc[1][1] = MFMA16(ah1, bl1, acc[1][1], 0, 0, 0);
      acc[0][0] = MFMA16(al0, bh0, acc[0][0], 0, 0, 0);
      acc[0][1] = MFMA16(al0, bh1, acc[0][1], 0, 0, 0);
      acc[1][0] = MFMA16(al1, bh0, acc[1][0], 0, 0, 0);
      acc[1][1] = MFMA16(al1, bh1, acc[1][1], 0, 0, 0);
    }
    buf ^= 1;
  }

  // epilogue: split acc -> hi/lo f16, LDS transpose to [n][d], coalesced stores
  __syncthreads();
  _Float16* Eh = (_Float16*)sm;             // [128][132]
  _Float16* El = (_Float16*)(sm + 33792);
#pragma unroll
  for (int mt = 0; mt < 2; mt++)
#pragma unroll
    for (int nt = 0; nt < 2; nt++) {
      int n_l = wn * 64 + nt * 32 + lr;
#pragma unroll
      for (int g = 0; g < 4; g++) {
        int d_l = wm * 64 + mt * 32 + 8 * g + 4 * lh;
        f16x4 h, l;
#pragma unroll
        for (int e = 0; e < 4; e++) {
          float x = acc[mt][nt][4 * g + e];  // reg 4g+e -> row e + 8g + 4lh
          _Float16 hh = (_Float16)x;
          h[e] = hh;
          l[e] = (_Float16)(x - (float)hh);
        }
        *(f16x4*)&Eh[n_l * 132 + d_l] = h;
        *(f16x4*)&El[n_l * 132 + d_l] = l;
      }
    }
  __syncthreads();
  _Float16* gh = zeT_h + ((size_t)b * NN_ + n0) * DD + d0;
  _Float16* gl = zeT_l + ((size_t)b * NN_ + n0) * DD + d0;
#pragma unroll
  for (int i = 0; i < 16; i++) {
    int n = i * 8 + w * 2 + lh;
    int d = 4 * lr;
    *(f16x4*)&gh[(size_t)n * DD + d] = *(const f16x4*)&Eh[n * 132 + d];
    *(f16x4*)&gl[(size_t)n * DD + d] = *(const f16x4*)&El[n * 132 + d];
  }
}

// ---------- kernel 3: MFMA split-f16 partial argmin over one K-split ----------
__global__ __launch_bounds__(256) void k_argmin(const _Float16* __restrict__ emb_h,
                                                const _Float16* __restrict__ emb_l,
                                                const _Float16* __restrict__ zeT_h,
                                                const _Float16* __restrict__ zeT_l,
                                                const float* __restrict__ esq,
                                                float* __restrict__ pval,
                                                int* __restrict__ pidx) {
  __shared__ __align__(16) char sm[69632];
  const int t = threadIdx.x;
  const int w = t >> 6, lane = t & 63;
  const int lr = lane & 31, lh = lane >> 5;
  const int wm = w & 1, wn = w >> 1;
  const int b = blockIdx.y, n0 = blockIdx.x * 128, ks = blockIdx.z;
  const int kbase = ks * KPER;

  float* esqs = (float*)(sm + 65536);
  *(float2*)&esqs[2 * t] = *(const float2*)&esq[kbase + 2 * t];

  const _Float16* zb_h = zeT_h + ((size_t)b * NN_ + n0) * DD;
  const _Float16* zb_l = zeT_l + ((size_t)b * NN_ + n0) * DD;

  auto stage = [&](int buf, int kt, int dc) {
    const int k0 = kbase + kt * 128;
    const int q = lane & 3, rr = lane >> 2;
    const int rb0 = 32 * w;
#pragma unroll
    for (int j = 0; j < 2; j++) {
      int rb = rb0 + 16 * j;
      int r = rb + rr;
      int col = dc + 8 * q;
      size_t eo = (size_t)(k0 + r) * DD + col;
      size_t zo = (size_t)r * DD + col;
      char* lb = sm + (size_t)buf * 8192 + rb * 64;
      GLDS16(emb_h + eo, lb);
      GLDS16(emb_l + eo, lb + 16384);
      GLDS16(zb_h + zo, lb + 32768);
      GLDS16(zb_l + zo, lb + 49152);
    }
  };

  f32x16 vzero;
#pragma unroll
  for (int i = 0; i < 16; i++) vzero[i] = 0.0f;

  float bestv[2];
  int   besti[2];
  bestv[0] = bestv[1] = 3.4e38f;
  besti[0] = besti[1] = 0;

  stage(0, 0, 0);
  int buf = 0;
  for (int kt = 0; kt < 4; kt++) {
    f32x16 acc00 = vzero, acc01 = vzero, acc10 = vzero, acc11 = vzero;
    for (int dc = 0; dc < DD; dc += 32) {
      __syncthreads();
      if (dc + 32 < DD) stage(buf ^ 1, kt, dc + 32);
      else if (kt < 3) stage(buf ^ 1, kt + 1, 0);
      const _Float16* EHb = (const _Float16*)(sm + buf * 8192);
      const _Float16* ELb = (const _Float16*)(sm + 16384 + buf * 8192);
      const _Float16* ZHb = (const _Float16*)(sm + 32768 + buf * 8192);
      const _Float16* ZLb = (const _Float16*)(sm + 49152 + buf * 8192);
#pragma unroll
      for (int s = 0; s < 2; s++) {
        const int acol = s * 16 + lh * 8;
        const int ar0 = (wm * 64 + lr) * 32 + acol;
        const int ar1 = (wm * 64 + 32 + lr) * 32 + acol;
        const int br0 = (wn * 64 + lr) * 32 + acol;
        const int br1 = (wn * 64 + 32 + lr) * 32 + acol;
        f16x8 ah0 = *(const f16x8*)(EHb + ar0);
        f16x8 ah1 = *(const f16x8*)(EHb + ar1);
        f16x8 al0 = *(const f16x8*)(ELb + ar0);
        f16x8 al1 = *(const f16x8*)(ELb + ar1);
        f16x8 bh0 = *(const f16x8*)(ZHb + br0);
        f16x8 bh1 = *(const f16x8*)(ZHb + br1);
        f16x8 bl0 = *(const f16x8*)(ZLb + br0);
        f16x8 bl1 = *(const f16x8*)(ZLb + br1);
        acc00 = MFMA16(ah0, bh0, acc00, 0, 0, 0);
        acc01 = MFMA16(ah0, bh1, acc01, 0, 0, 0);
        acc10 = MFMA16(ah1, bh0, acc10, 0, 0, 0);
        acc11 = MFMA16(ah1, bh1, acc11, 0, 0, 0);
        acc00 = MFMA16(ah0, bl0, acc00, 0, 0, 0);
        acc01 = MFMA16(ah0, bl1, acc01, 0, 0, 0);
        acc10 = MFMA16(ah1, bl0, acc10, 0, 0, 0);
        acc11 = MFMA16(ah1, bl1, acc11, 0, 0, 0);
        acc00 = MFMA16(al0, bh0, acc00, 0, 0, 0);
        acc01 = MFMA16(al0, bh1, acc01, 0, 0, 0);
        acc10 = MFMA16(al1, bh0, acc10, 0, 0, 0);
        acc11 = MFMA16(al1, bh1, acc11, 0, 0, 0);
      }
      buf ^= 1;
    }
#pragma unroll
    for (int mt = 0; mt < 2; mt++)
#pragma unroll
      for (int nt = 0; nt < 2; nt++) {
        const f32x16& a = (mt == 0) ? (nt == 0 ? acc00 : acc01)
                                    : (nt == 0 ? acc10 : acc11);
#pragma unroll
        for (int r = 0; r < 16; r++) {
          int kl = kt * 128 + wm * 64 + mt * 32 + (r & 3) + 8 * (r >> 2) + 4 * lh;
          float d2 = esqs[kl] - 2.0f * a[r];
          int kg = kbase + kl;
          if (d2 < bestv[nt] || (d2 == bestv[nt] && kg < besti[nt])) {
            bestv[nt] = d2; besti[nt] = kg;
          }
        }
      }
  }

#pragma unroll
  for (int nt = 0; nt < 2; nt++) {
    float ov = __shfl_xor(bestv[nt], 32, 64);
    int   oi = __shfl_xor(besti[nt], 32, 64);
    if (ov < bestv[nt] || (ov == bestv[nt] && oi < besti[nt])) {
      bestv[nt] = ov; besti[nt] = oi;
    }
  }
  float* pv = (float*)(sm + 67584);
  int*   pi = (int*)(sm + 68608);
  __syncthreads();
  if (lh == 0) {
#pragma unroll
    for (int nt = 0; nt < 2; nt++) {
      pv[(w * 2 + nt) * 32 + lr] = bestv[nt];
      pi[(w * 2 + nt) * 32 + lr] = besti[nt];
    }
  }
  __syncthreads();
  if (t < 128) {
    int wn2 = t >> 6, nt = (t >> 5) & 1, nl = t & 31;
    int i0 = ((2 * wn2 + 0) * 2 + nt) * 32 + nl;
    int i1 = ((2 * wn2 + 1) * 2 + nt) * 32 + nl;
    float v0 = pv[i0], v1 = pv[i1];
    int   j0 = pi[i0], j1 = pi[i1];
    if (v1 < v0 || (v1 == v0 && j1 < j0)) { v0 = v1; j0 = j1; }
    size_t o = ((size_t)ks * B_ + b) * NN_ + n0 + t;
    pval[o] = v0;
    pidx[o] = j0;
  }
}

// ---------- kernel 4: merge partials; gather out = emb[ind]; scatter EMA stats ----------
__global__ __launch_bounds__(256) void k_gs(const float* __restrict__ emb,
                                            const _Float16* __restrict__ zeT_h,
                                            const _Float16* __restrict__ zeT_l,
                                            const float* __restrict__ pval,
                                            const int* __restrict__ pidx,
                                            float* __restrict__ out,
                                            float* __restrict__ z_sum,
                                            float* __restrict__ n_sum) {
  __shared__ __align__(16) float E[64][257];
  __shared__ int idxl[64];
  const int t = threadIdx.x;
  const int w = t >> 6, lane = t & 63;
  const int b  = blockIdx.y;
  const int n0 = blockIdx.x * 64;

  if (t < 64) {
    size_t base = (size_t)b * NN_ + n0 + t;
    float bv = pval[base];
    int   bi = pidx[base];
#pragma unroll
    for (int ks = 1; ks < KSPLIT; ks++) {
      float v = pval[(size_t)ks * B_ * NN_ + base];
      int  ii = pidx[(size_t)ks * B_ * NN_ + base];
      if (v < bv || (v == bv && ii < bi)) { bv = v; bi = ii; }
    }
    idxl[t] = bi;
  }
  __syncthreads();

  // phase A: stage emb rows per local n, then coalesced out writes
  for (int i = 0; i < 16; i++) {
    int cid = t + 256 * i;
    int r = cid >> 6, q = cid & 63;
    float4 v = *(const float4*)&emb[(size_t)idxl[r] * DD + 4 * q];
    float* vp = (float*)&v;
    E[r][4 * q + 0] = vp[0];
    E[r][4 * q + 1] = vp[1];
    E[r][4 * q + 2] = vp[2];
    E[r][4 * q + 3] = vp[3];
  }
  __syncthreads();
  const int nn = t & 63, dd = t >> 6;
  float* outb = out + (size_t)b * DD * NN_ + n0;
  for (int i = 0; i < 64; i++) {
    int d = 4 * i + dd;
    outb[(size_t)d * NN_ + nn] = E[nn][d];
  }

  // phase B: scatter ze (reconstructed h+l) into z_sum; zeT rows are d-contiguous
  if (t < 64) atomicAdd(&n_sum[idxl[t]], 1.0f);
#pragma unroll 1
  for (int i = 0; i < 16; i++) {
    int nl = i * 4 + w;
    int kidx = idxl[nl];
    size_t ro = ((size_t)b * NN_ + n0 + nl) * DD + 4 * lane;
    f16x4 h = *(const f16x4*)&zeT_h[ro];
    f16x4 l = *(const f16x4*)&zeT_l[ro];
    float* zs = &z_sum[(size_t)kidx * DD + 4 * lane];
#pragma unroll
    for (int e = 0; e < 4; e++) atomicAdd(&zs[e], (float)h[e] + (float)l[e]);
  }
}

// ---------- kernel 5: EMA update ----------
__global__ __launch_bounds__(256) void k_ema(const float* __restrict__ ema_numer,
                                             const float* __restrict__ ema_denom,
                                             const float* __restrict__ z_sum,
                                             const float* __restrict__ n_sum,
                                             float* __restrict__ out_numer,
                                             float* __restrict__ out_denom) {
  const float G  = 0.99f;
  const float OG = 0.009999999776482582f;
  int i = blockIdx.x * 256 + threadIdx.x;
  if (i < KK * DD) {
    out_numer[i] = G * ema_numer[i] + OG * z_sum[i];
  } else {
    int j = i - KK * DD;
    if (j < KK) out_denom[j] = G * ema_denom[j] + OG * n_sum[j];
  }
}

extern "C" void kernel_launch(void* const* d_in, const int* in_sizes, int n_in,
                              void* d_out, int out_size, void* d_ws, size_t ws_size,
                              hipStream_t stream) {
  (void)in_sizes; (void)n_in; (void)out_size; (void)ws_size;
  const float* z         = (const float*)d_in[0];
  const float* W         = (const float*)d_in[1];
  const float* emb       = (const float*)d_in[2];
  const float* ema_numer = (const float*)d_in[3];
  const float* ema_denom = (const float*)d_in[4];

  float* out       = (float*)d_out;                        // (8,256,4096)
  float* out_numer = out + (size_t)B_ * DD * NN_;
  float* out_denom = out_numer + (size_t)KK * DD;

  const size_t ZET = (size_t)B_ * NN_ * DD;                // 8388608
  _Float16* zeT_h = (_Float16*)d_ws;                       // 16 MB
  _Float16* zeT_l = zeT_h + ZET;                           // 16 MB
  float* esq  = (float*)(zeT_l + ZET);                     // 2048
  float* nsum = esq + KK;                                  // 2048
  float* zsum = nsum + KK;                                 // 524288
  float* pval = zsum + (size_t)KK * DD;                    // 131072
  int*   pidx = (int*)(pval + (size_t)KSPLIT * B_ * NN_);  // 131072
  _Float16* emb_h = (_Float16*)(pidx + (size_t)KSPLIT * B_ * NN_);
  _Float16* emb_l = emb_h + (size_t)KK * DD;

  hipMemsetAsync(nsum, 0, (size_t)(KK + KK * DD) * sizeof(float), stream);

  k_esq<<<dim3(KK / 4), 256, 0, stream>>>(emb, esq, emb_h, emb_l);
  k_ze<<<dim3(NN_ / 128, DD / 128, B_), 256, 0, stream>>>(W, z, zeT_h, zeT_l);
  k_argmin<<<dim3(NN_ / 128, B_, KSPLIT), 256, 0, stream>>>(emb_h, emb_l, zeT_h, zeT_l,
                                                            esq, pval, pidx);
  k_gs<<<dim3(NN_ / 64, B_), 256, 0, stream>>>(emb, zeT_h, zeT_l, pval, pidx,
                                               out, zsum, nsum);
  k_ema<<<dim3((KK * DD + KK) / 256), 256, 0, stream>>>(ema_numer, ema_denom, zsum, nsum,
                                                        out_numer, out_denom);
}

// Round 5
// 312.880 us; speedup vs baseline: 2.8589x; 1.2158x over previous
//
#include <hip/hip_runtime.h>

#define B_   8
#define CIN  512
#define NN_  4096
#define DD   256
#define KK   2048
#define KSPLIT 4
#define KPER (KK / KSPLIT)   // 512
#define NG   (B_ * NN_)      // 32768 total samples

typedef _Float16 f16x8 __attribute__((ext_vector_type(8)));
typedef _Float16 f16x4 __attribute__((ext_vector_type(4)));
typedef float    f32x16 __attribute__((ext_vector_type(16)));

#define MFMA16 __builtin_amdgcn_mfma_f32_32x32x16_f16

// async global->LDS, 16B per lane; LDS dest is wave-uniform base + lane*16
#define GLDS16(gp, lp) __builtin_amdgcn_global_load_lds( \
    (const __attribute__((address_space(1))) void*)(gp), \
    (__attribute__((address_space(3))) void*)(lp), 16, 0, 0)

// ---------- kernel 1: esq[k] = sum_d emb[k,d]^2 ; emit emb hi/lo f16 ----------
__global__ __launch_bounds__(256) void k_esq(const float* __restrict__ emb,
                                             float* __restrict__ esq,
                                             _Float16* __restrict__ emb_h,
                                             _Float16* __restrict__ emb_l) {
  int t = threadIdx.x;
  int lane = t & 63;
  int k = blockIdx.x * 4 + (t >> 6);
  float4 v = *(const float4*)&emb[(size_t)k * DD + 4 * lane];
  float s = v.x * v.x + v.y * v.y + v.z * v.z + v.w * v.w;
  f16x4 h, l;
  float* vp = (float*)&v;
#pragma unroll
  for (int i = 0; i < 4; i++) {
    _Float16 hh = (_Float16)vp[i];
    h[i] = hh;
    l[i] = (_Float16)(vp[i] - (float)hh);
  }
  *(f16x4*)&emb_h[(size_t)k * DD + 4 * lane] = h;
  *(f16x4*)&emb_l[(size_t)k * DD + 4 * lane] = l;
  for (int off = 32; off > 0; off >>= 1) s += __shfl_down(s, off, 64);
  if (lane == 0) esq[k] = s;
}

// ---------- kernel 2: MFMA split-f16 conv: zeT_{h,l}[b,n,d] = sum_c W[d,c] z[b,c,n] ----------
__global__ __launch_bounds__(256) void k_ze(const float* __restrict__ W,
                                            const float* __restrict__ z,
                                            _Float16* __restrict__ zeT_h,
                                            _Float16* __restrict__ zeT_l) {
  __shared__ __align__(16) char sm[73728];
  const int t = threadIdx.x;
  const int w = t >> 6, lane = t & 63;
  const int lr = lane & 31, lh = lane >> 5;
  const int wm = w & 1, wn = w >> 1;
  const int b = blockIdx.z, d0 = blockIdx.y * 128, n0 = blockIdx.x * 128;
  const float* zb = z + (size_t)b * CIN * NN_ + n0;

  _Float16* Ah = (_Float16*)sm;             // [2][128][40]
  _Float16* Al = (_Float16*)(sm + 20480);   // [2][128][40]
  float*    Zs = (float*)(sm + 40960);      // [2][32][128]

  auto stageA = [&](int buf, int c0) {
#pragma unroll
    for (int i = 0; i < 4; i++) {
      int fid = i * 256 + t;
      int d = fid >> 3, q = fid & 7;
      float4 v = *(const float4*)&W[(size_t)(d0 + d) * CIN + c0 + 4 * q];
      float* vp = (float*)&v;
      f16x4 h, l;
#pragma unroll
      for (int e = 0; e < 4; e++) {
        _Float16 hh = (_Float16)vp[e];
        h[e] = hh;
        l[e] = (_Float16)(vp[e] - (float)hh);
      }
      *(f16x4*)&Ah[(size_t)(buf * 128 + d) * 40 + 4 * q] = h;
      *(f16x4*)&Al[(size_t)(buf * 128 + d) * 40 + 4 * q] = l;
    }
  };
  auto stageZ = [&](int buf, int c0) {
#pragma unroll
    for (int i = 0; i < 4; i++) {
      int r = 8 * w + 2 * i;
      float* lbase = Zs + (size_t)buf * 4096 + r * 128;
      const float* gp = zb + (size_t)(c0 + r + lh) * NN_ + 4 * lr;
      GLDS16(gp, lbase);
    }
  };

  f32x16 acc[2][2];
#pragma unroll
  for (int mt = 0; mt < 2; mt++)
#pragma unroll
    for (int nt = 0; nt < 2; nt++)
#pragma unroll
      for (int i = 0; i < 16; i++) acc[mt][nt][i] = 0.0f;

  stageA(0, 0);
  stageZ(0, 0);
  int buf = 0;
  for (int c0 = 0; c0 < CIN; c0 += 32) {
    __syncthreads();
    if (c0 + 32 < CIN) { stageA(buf ^ 1, c0 + 32); stageZ(buf ^ 1, c0 + 32); }
    const _Float16* AhB = Ah + (size_t)buf * 128 * 40;
    const _Float16* AlB = Al + (size_t)buf * 128 * 40;
    const float*    ZsB = Zs + (size_t)buf * 4096;
#pragma unroll
    for (int s = 0; s < 2; s++) {
      const int ca = 16 * s + 8 * lh;
      f16x8 ah0 = *(const f16x8*)&AhB[(wm * 64 + lr) * 40 + ca];
      f16x8 ah1 = *(const f16x8*)&AhB[(wm * 64 + 32 + lr) * 40 + ca];
      f16x8 al0 = *(const f16x8*)&AlB[(wm * 64 + lr) * 40 + ca];
      f16x8 al1 = *(const f16x8*)&AlB[(wm * 64 + 32 + lr) * 40 + ca];
      f16x8 bh0, bl0, bh1, bl1;
#pragma unroll
      for (int j = 0; j < 8; j++) {
        float x0 = ZsB[(ca + j) * 128 + wn * 64 + lr];
        float x1 = ZsB[(ca + j) * 128 + wn * 64 + 32 + lr];
        _Float16 h0 = (_Float16)x0;
        bh0[j] = h0;
        bl0[j] = (_Float16)(x0 - (float)h0);
        _Float16 h1 = (_Float16)x1;
        bh1[j] = h1;
        bl1[j] = (_Float16)(x1 - (float)h1);
      }
      acc[0][0] = MFMA16(ah0, bh0, acc[0][0], 0, 0, 0);
      acc[0][1] = MFMA16(ah0, bh1, acc[0][1], 0, 0, 0);
      acc[1][0] = MFMA16(ah1, bh0, acc[1][0], 0, 0, 0);
      acc[1][1] = MFMA16(ah1, bh1, acc[1][1], 0, 0, 0);
      acc[0][0] = MFMA16(ah0, bl0, acc[0][0], 0, 0, 0);
      acc[0][1] = MFMA16(ah0, bl1, acc[0][1], 0, 0, 0);
      acc[1][0] = MFMA16(ah1, bl0, acc[1][0], 0, 0, 0);
      acc[1][1] = MFMA16(ah1, bl1, acc[1][1], 0, 0, 0);
      acc[0][0] = MFMA16(al0, bh0, acc[0][0], 0, 0, 0);
      acc[0][1] = MFMA16(al0, bh1, acc[0][1], 0, 0, 0);
      acc[1][0] = MFMA16(al1, bh0, acc[1][0], 0, 0, 0);
      acc[1][1] = MFMA16(al1, bh1, acc[1][1], 0, 0, 0);
    }
    buf ^= 1;
  }

  __syncthreads();
  _Float16* Eh = (_Float16*)sm;             // [128][132]
  _Float16* El = (_Float16*)(sm + 33792);
#pragma unroll
  for (int mt = 0; mt < 2; mt++)
#pragma unroll
    for (int nt = 0; nt < 2; nt++) {
      int n_l = wn * 64 + nt * 32 + lr;
#pragma unroll
      for (int g = 0; g < 4; g++) {
        int d_l = wm * 64 + mt * 32 + 8 * g + 4 * lh;
        f16x4 h, l;
#pragma unroll
        for (int e = 0; e < 4; e++) {
          float x = acc[mt][nt][4 * g + e];
          _Float16 hh = (_Float16)x;
          h[e] = hh;
          l[e] = (_Float16)(x - (float)hh);
        }
        *(f16x4*)&Eh[n_l * 132 + d_l] = h;
        *(f16x4*)&El[n_l * 132 + d_l] = l;
      }
    }
  __syncthreads();
  _Float16* gh = zeT_h + ((size_t)b * NN_ + n0) * DD + d0;
  _Float16* gl = zeT_l + ((size_t)b * NN_ + n0) * DD + d0;
#pragma unroll
  for (int i = 0; i < 16; i++) {
    int n = i * 8 + w * 2 + lh;
    int d = 4 * lr;
    *(f16x4*)&gh[(size_t)n * DD + d] = *(const f16x4*)&Eh[n * 132 + d];
    *(f16x4*)&gl[(size_t)n * DD + d] = *(const f16x4*)&El[n * 132 + d];
  }
}

// ---------- kernel 3: MFMA split-f16 partial argmin over one K-split ----------
__global__ __launch_bounds__(256) void k_argmin(const _Float16* __restrict__ emb_h,
                                                const _Float16* __restrict__ emb_l,
                                                const _Float16* __restrict__ zeT_h,
                                                const _Float16* __restrict__ zeT_l,
                                                const float* __restrict__ esq,
                                                float* __restrict__ pval,
                                                int* __restrict__ pidx) {
  __shared__ __align__(16) char sm[69632];
  const int t = threadIdx.x;
  const int w = t >> 6, lane = t & 63;
  const int lr = lane & 31, lh = lane >> 5;
  const int wm = w & 1, wn = w >> 1;
  const int b = blockIdx.y, n0 = blockIdx.x * 128, ks = blockIdx.z;
  const int kbase = ks * KPER;

  float* esqs = (float*)(sm + 65536);
  *(float2*)&esqs[2 * t] = *(const float2*)&esq[kbase + 2 * t];

  const _Float16* zb_h = zeT_h + ((size_t)b * NN_ + n0) * DD;
  const _Float16* zb_l = zeT_l + ((size_t)b * NN_ + n0) * DD;

  auto stage = [&](int buf, int kt, int dc) {
    const int k0 = kbase + kt * 128;
    const int q = lane & 3, rr = lane >> 2;
    const int rb0 = 32 * w;
#pragma unroll
    for (int j = 0; j < 2; j++) {
      int rb = rb0 + 16 * j;
      int r = rb + rr;
      int col = dc + 8 * q;
      size_t eo = (size_t)(k0 + r) * DD + col;
      size_t zo = (size_t)r * DD + col;
      char* lb = sm + (size_t)buf * 8192 + rb * 64;
      GLDS16(emb_h + eo, lb);
      GLDS16(emb_l + eo, lb + 16384);
      GLDS16(zb_h + zo, lb + 32768);
      GLDS16(zb_l + zo, lb + 49152);
    }
  };

  f32x16 vzero;
#pragma unroll
  for (int i = 0; i < 16; i++) vzero[i] = 0.0f;

  float bestv[2];
  int   besti[2];
  bestv[0] = bestv[1] = 3.4e38f;
  besti[0] = besti[1] = 0;

  stage(0, 0, 0);
  int buf = 0;
  for (int kt = 0; kt < 4; kt++) {
    f32x16 acc00 = vzero, acc01 = vzero, acc10 = vzero, acc11 = vzero;
    for (int dc = 0; dc < DD; dc += 32) {
      __syncthreads();
      if (dc + 32 < DD) stage(buf ^ 1, kt, dc + 32);
      else if (kt < 3) stage(buf ^ 1, kt + 1, 0);
      const _Float16* EHb = (const _Float16*)(sm + buf * 8192);
      const _Float16* ELb = (const _Float16*)(sm + 16384 + buf * 8192);
      const _Float16* ZHb = (const _Float16*)(sm + 32768 + buf * 8192);
      const _Float16* ZLb = (const _Float16*)(sm + 49152 + buf * 8192);
#pragma unroll
      for (int s = 0; s < 2; s++) {
        const int acol = s * 16 + lh * 8;
        const int ar0 = (wm * 64 + lr) * 32 + acol;
        const int ar1 = (wm * 64 + 32 + lr) * 32 + acol;
        const int br0 = (wn * 64 + lr) * 32 + acol;
        const int br1 = (wn * 64 + 32 + lr) * 32 + acol;
        f16x8 ah0 = *(const f16x8*)(EHb + ar0);
        f16x8 ah1 = *(const f16x8*)(EHb + ar1);
        f16x8 al0 = *(const f16x8*)(ELb + ar0);
        f16x8 al1 = *(const f16x8*)(ELb + ar1);
        f16x8 bh0 = *(const f16x8*)(ZHb + br0);
        f16x8 bh1 = *(const f16x8*)(ZHb + br1);
        f16x8 bl0 = *(const f16x8*)(ZLb + br0);
        f16x8 bl1 = *(const f16x8*)(ZLb + br1);
        acc00 = MFMA16(ah0, bh0, acc00, 0, 0, 0);
        acc01 = MFMA16(ah0, bh1, acc01, 0, 0, 0);
        acc10 = MFMA16(ah1, bh0, acc10, 0, 0, 0);
        acc11 = MFMA16(ah1, bh1, acc11, 0, 0, 0);
        acc00 = MFMA16(ah0, bl0, acc00, 0, 0, 0);
        acc01 = MFMA16(ah0, bl1, acc01, 0, 0, 0);
        acc10 = MFMA16(ah1, bl0, acc10, 0, 0, 0);
        acc11 = MFMA16(ah1, bl1, acc11, 0, 0, 0);
        acc00 = MFMA16(al0, bh0, acc00, 0, 0, 0);
        acc01 = MFMA16(al0, bh1, acc01, 0, 0, 0);
        acc10 = MFMA16(al1, bh0, acc10, 0, 0, 0);
        acc11 = MFMA16(al1, bh1, acc11, 0, 0, 0);
      }
      buf ^= 1;
    }
#pragma unroll
    for (int mt = 0; mt < 2; mt++)
#pragma unroll
      for (int nt = 0; nt < 2; nt++) {
        const f32x16& a = (mt == 0) ? (nt == 0 ? acc00 : acc01)
                                    : (nt == 0 ? acc10 : acc11);
#pragma unroll
        for (int r = 0; r < 16; r++) {
          int kl = kt * 128 + wm * 64 + mt * 32 + (r & 3) + 8 * (r >> 2) + 4 * lh;
          float d2 = esqs[kl] - 2.0f * a[r];
          int kg = kbase + kl;
          if (d2 < bestv[nt] || (d2 == bestv[nt] && kg < besti[nt])) {
            bestv[nt] = d2; besti[nt] = kg;
          }
        }
      }
  }

#pragma unroll
  for (int nt = 0; nt < 2; nt++) {
    float ov = __shfl_xor(bestv[nt], 32, 64);
    int   oi = __shfl_xor(besti[nt], 32, 64);
    if (ov < bestv[nt] || (ov == bestv[nt] && oi < besti[nt])) {
      bestv[nt] = ov; besti[nt] = oi;
    }
  }
  float* pv = (float*)(sm + 67584);
  int*   pi = (int*)(sm + 68608);
  __syncthreads();
  if (lh == 0) {
#pragma unroll
    for (int nt = 0; nt < 2; nt++) {
      pv[(w * 2 + nt) * 32 + lr] = bestv[nt];
      pi[(w * 2 + nt) * 32 + lr] = besti[nt];
    }
  }
  __syncthreads();
  if (t < 128) {
    int wn2 = t >> 6, nt = (t >> 5) & 1, nl = t & 31;
    int i0 = ((2 * wn2 + 0) * 2 + nt) * 32 + nl;
    int i1 = ((2 * wn2 + 1) * 2 + nt) * 32 + nl;
    float v0 = pv[i0], v1 = pv[i1];
    int   j0 = pi[i0], j1 = pi[i1];
    if (v1 < v0 || (v1 == v0 && j1 < j0)) { v0 = v1; j0 = j1; }
    size_t o = ((size_t)ks * B_ + b) * NN_ + n0 + t;
    pval[o] = v0;
    pidx[o] = j0;
  }
}

// ---------- kernel 4: merge K-split partials -> mind ; histogram -> hist ----------
__global__ __launch_bounds__(256) void k_histm(const float* __restrict__ pval,
                                               const int* __restrict__ pidx,
                                               int* __restrict__ mind,
                                               int* __restrict__ hist) {
  __shared__ int h[KK];
  const int t = threadIdx.x;
#pragma unroll
  for (int i = 0; i < 8; i++) h[t + 256 * i] = 0;
  __syncthreads();
  const int base = blockIdx.x * 2048;
#pragma unroll
  for (int i = 0; i < 8; i++) {
    int g = base + i * 256 + t;
    float bv = pval[g];
    int   bi = pidx[g];
#pragma unroll
    for (int ks = 1; ks < KSPLIT; ks++) {
      float v = pval[(size_t)ks * NG + g];
      int  ii = pidx[(size_t)ks * NG + g];
      if (v < bv || (v == bv && ii < bi)) { bv = v; bi = ii; }
    }
    mind[g] = bi;
    atomicAdd(&h[bi], 1);
  }
  __syncthreads();
#pragma unroll
  for (int i = 0; i < 8; i++) {
    int v = h[t + 256 * i];
    if (v) atomicAdd(&hist[t + 256 * i], v);
  }
}

// ---------- kernel 5: exclusive prefix sum of hist -> cursor ; n_sum floats ----------
__global__ __launch_bounds__(256) void k_scan(const int* __restrict__ hist,
                                              int* __restrict__ cursor,
                                              float* __restrict__ nsumf) {
  __shared__ int ps[256];
  const int t = threadIdx.x;
  int c[8], s = 0;
#pragma unroll
  for (int e = 0; e < 8; e++) { c[e] = hist[8 * t + e]; s += c[e]; }
  ps[t] = s;
  __syncthreads();
  for (int off = 1; off < 256; off <<= 1) {
    int v = (t >= off) ? ps[t - off] : 0;
    __syncthreads();
    ps[t] += v;
    __syncthreads();
  }
  int run = ps[t] - s;  // exclusive base
#pragma unroll
  for (int e = 0; e < 8; e++) {
    cursor[8 * t + e] = run;
    nsumf[8 * t + e] = (float)c[e];
    run += c[e];
  }
}

// ---------- kernel 6: scatter sample ids into sorted order (packed k<<15|g) ----------
__global__ __launch_bounds__(256) void k_pos(const int* __restrict__ mind,
                                             int* __restrict__ cursor,
                                             int* __restrict__ sortp) {
  int g = blockIdx.x * 256 + threadIdx.x;
  int k = mind[g];
  int p = atomicAdd(&cursor[k], 1);
  sortp[p] = (k << 15) | g;
}

// ---------- kernel 7: out[b,d,n] = emb[mind[b,n], d] ----------
__global__ __launch_bounds__(256) void k_out(const float* __restrict__ emb,
                                             const int* __restrict__ mind,
                                             float* __restrict__ out) {
  __shared__ __align__(16) float E[64][257];
  __shared__ int idxl[64];
  const int t = threadIdx.x;
  const int b  = blockIdx.y;
  const int n0 = blockIdx.x * 64;
  if (t < 64) idxl[t] = mind[(size_t)b * NN_ + n0 + t];
  __syncthreads();

  for (int i = 0; i < 16; i++) {
    int cid = t + 256 * i;
    int r = cid >> 6, q = cid & 63;
    float4 v = *(const float4*)&emb[(size_t)idxl[r] * DD + 4 * q];
    float* vp = (float*)&v;
    E[r][4 * q + 0] = vp[0];
    E[r][4 * q + 1] = vp[1];
    E[r][4 * q + 2] = vp[2];
    E[r][4 * q + 3] = vp[3];
  }
  __syncthreads();
  const int nq = t & 15, dg = t >> 4;
  float* outb = out + (size_t)b * DD * NN_ + n0;
#pragma unroll
  for (int i = 0; i < 16; i++) {
    int d = i * 16 + dg;
    float4 v = make_float4(E[4 * nq + 0][d], E[4 * nq + 1][d],
                           E[4 * nq + 2][d], E[4 * nq + 3][d]);
    *(float4*)&outb[(size_t)d * NN_ + 4 * nq] = v;
  }
}

// ---------- kernel 8: segment-sum over sorted runs -> z_sum ----------
// each wave: 64 sorted entries; register-accumulate runs; atomic only at run ends
__global__ __launch_bounds__(256) void k_zsum(const int* __restrict__ sortp,
                                              const _Float16* __restrict__ zeT_h,
                                              const _Float16* __restrict__ zeT_l,
                                              float* __restrict__ z_sum) {
  __shared__ int sg[256];
  const int t = threadIdx.x;
  const int w = t >> 6, lane = t & 63;
  sg[t] = sortp[blockIdx.x * 256 + t];
  __syncthreads();
  const int base = w * 64;
  float acc[4] = {0.f, 0.f, 0.f, 0.f};
  int cur = sg[base] >> 15;
  for (int j = 0; j < 64; j++) {
    int e = sg[base + j];
    int k = e >> 15, g = e & 32767;
    if (k != cur) {
      float* zs = &z_sum[(size_t)cur * DD + 4 * lane];
#pragma unroll
      for (int x = 0; x < 4; x++) { atomicAdd(&zs[x], acc[x]); acc[x] = 0.f; }
      cur = k;
    }
    f16x4 h = *(const f16x4*)&zeT_h[(size_t)g * DD + 4 * lane];
    f16x4 l = *(const f16x4*)&zeT_l[(size_t)g * DD + 4 * lane];
#pragma unroll
    for (int x = 0; x < 4; x++) acc[x] += (float)h[x] + (float)l[x];
  }
  float* zs = &z_sum[(size_t)cur * DD + 4 * lane];
#pragma unroll
  for (int x = 0; x < 4; x++) atomicAdd(&zs[x], acc[x]);
}

// ---------- kernel 9: EMA update ----------
__global__ __launch_bounds__(256) void k_ema(const float* __restrict__ ema_numer,
                                             const float* __restrict__ ema_denom,
                                             const float* __restrict__ z_sum,
                                             const float* __restrict__ nsumf,
                                             float* __restrict__ out_numer,
                                             float* __restrict__ out_denom) {
  const float G  = 0.99f;
  const float OG = 0.009999999776482582f;
  int i = blockIdx.x * 256 + threadIdx.x;
  if (i < KK * DD) {
    out_numer[i] = G * ema_numer[i] + OG * z_sum[i];
  } else {
    int j = i - KK * DD;
    if (j < KK) out_denom[j] = G * ema_denom[j] + OG * nsumf[j];
  }
}

extern "C" void kernel_launch(void* const* d_in, const int* in_sizes, int n_in,
                              void* d_out, int out_size, void* d_ws, size_t ws_size,
                              hipStream_t stream) {
  (void)in_sizes; (void)n_in; (void)out_size; (void)ws_size;
  const float* z         = (const float*)d_in[0];
  const float* W         = (const float*)d_in[1];
  const float* emb       = (const float*)d_in[2];
  const float* ema_numer = (const float*)d_in[3];
  const float* ema_denom = (const float*)d_in[4];

  float* out       = (float*)d_out;                        // (8,256,4096)
  float* out_numer = out + (size_t)B_ * DD * NN_;
  float* out_denom = out_numer + (size_t)KK * DD;

  const size_t ZET = (size_t)B_ * NN_ * DD;                // 8388608
  _Float16* zeT_h = (_Float16*)d_ws;                       // 16 MB
  _Float16* zeT_l = zeT_h + ZET;                           // 16 MB
  float* esq    = (float*)(zeT_l + ZET);                   // 2048
  float* zsum   = esq + KK;                                // 524288 (memset)
  int*   hist   = (int*)(zsum + (size_t)KK * DD);          // 2048   (memset, contiguous)
  int*   cursor = hist + KK;                               // 2048
  float* nsumf  = (float*)(cursor + KK);                   // 2048
  float* pval   = nsumf + KK;                              // 131072
  int*   pidx   = (int*)(pval + (size_t)KSPLIT * NG);      // 131072
  int*   mind   = pidx + (size_t)KSPLIT * NG;              // 32768
  int*   sortp  = mind + NG;                               // 32768
  _Float16* emb_h = (_Float16*)(sortp + NG);               // 524288 f16
  _Float16* emb_l = emb_h + (size_t)KK * DD;               // 524288 f16

  // zero zsum + hist in one shot (ws is poisoned before every timed call)
  hipMemsetAsync(zsum, 0, (size_t)(KK * DD + KK) * sizeof(float), stream);

  k_esq<<<dim3(KK / 4), 256, 0, stream>>>(emb, esq, emb_h, emb_l);
  k_ze<<<dim3(NN_ / 128, DD / 128, B_), 256, 0, stream>>>(W, z, zeT_h, zeT_l);
  k_argmin<<<dim3(NN_ / 128, B_, KSPLIT), 256, 0, stream>>>(emb_h, emb_l, zeT_h, zeT_l,
                                                            esq, pval, pidx);
  k_histm<<<dim3(NG / 2048), 256, 0, stream>>>(pval, pidx, mind, hist);
  k_scan<<<dim3(1), 256, 0, stream>>>(hist, cursor, nsumf);
  k_pos<<<dim3(NG / 256), 256, 0, stream>>>(mind, cursor, sortp);
  k_out<<<dim3(NN_ / 64, B_), 256, 0, stream>>>(emb, mind, out);
  k_zsum<<<dim3(NG / 256), 256, 0, stream>>>(sortp, zeT_h, zeT_l, zsum);
  k_ema<<<dim3((KK * DD + KK) / 256), 256, 0, stream>>>(ema_numer, ema_denom, zsum, nsumf,
                                                        out_numer, out_denom);
}

// Round 6
// 307.408 us; speedup vs baseline: 2.9098x; 1.0178x over previous
//
#include <hip/hip_runtime.h>

#define B_   8
#define CIN  512
#define NN_  4096
#define DD   256
#define KK   2048
#define KSPLIT 4
#define KPER (KK / KSPLIT)   // 512
#define NG   (B_ * NN_)      // 32768 total samples

typedef _Float16 f16x8 __attribute__((ext_vector_type(8)));
typedef _Float16 f16x4 __attribute__((ext_vector_type(4)));
typedef float    f32x16 __attribute__((ext_vector_type(16)));

#define MFMA16 __builtin_amdgcn_mfma_f32_32x32x16_f16

// async global->LDS, 16B per lane; LDS dest is wave-uniform base + lane*16
#define GLDS16(gp, lp) __builtin_amdgcn_global_load_lds( \
    (const __attribute__((address_space(1))) void*)(gp), \
    (__attribute__((address_space(3))) void*)(lp), 16, 0, 0)

// ---------- kernel 1: esq[k] = sum_d emb[k,d]^2 ; emit emb hi/lo f16 ----------
__global__ __launch_bounds__(256) void k_esq(const float* __restrict__ emb,
                                             float* __restrict__ esq,
                                             _Float16* __restrict__ emb_h,
                                             _Float16* __restrict__ emb_l) {
  int t = threadIdx.x;
  int lane = t & 63;
  int k = blockIdx.x * 4 + (t >> 6);
  float4 v = *(const float4*)&emb[(size_t)k * DD + 4 * lane];
  float s = v.x * v.x + v.y * v.y + v.z * v.z + v.w * v.w;
  f16x4 h, l;
  float* vp = (float*)&v;
#pragma unroll
  for (int i = 0; i < 4; i++) {
    _Float16 hh = (_Float16)vp[i];
    h[i] = hh;
    l[i] = (_Float16)(vp[i] - (float)hh);
  }
  *(f16x4*)&emb_h[(size_t)k * DD + 4 * lane] = h;
  *(f16x4*)&emb_l[(size_t)k * DD + 4 * lane] = l;
  for (int off = 32; off > 0; off >>= 1) s += __shfl_down(s, off, 64);
  if (lane == 0) esq[k] = s;
}

// ---------- kernel 2: MFMA split-f16 conv: zeT_{h,l}[b,n,d] = sum_c W[d,c] z[b,c,n] ----------
__global__ __launch_bounds__(256) void k_ze(const float* __restrict__ W,
                                            const float* __restrict__ z,
                                            _Float16* __restrict__ zeT_h,
                                            _Float16* __restrict__ zeT_l) {
  // Ah[2][128][32] f16 @0 (16384), Al @16384, Zs[2][32][128] f32 @32768 (32768)
  // epilogue overlay: Eh[128][132] f16 @0 (33792), El @33792 -> 67584 total
  __shared__ __align__(16) char sm[67584];
  const int t = threadIdx.x;
  const int w = t >> 6, lane = t & 63;
  const int lr = lane & 31, lh = lane >> 5;
  const int wm = w & 1, wn = w >> 1;
  const int swz = (lr >> 1) & 3;
  const int b = blockIdx.z, d0 = blockIdx.y * 128, n0 = blockIdx.x * 128;
  const float* zb = z + (size_t)b * CIN * NN_ + n0;

  _Float16* Ah = (_Float16*)sm;             // [2][128][32] swizzled 16B chunks
  _Float16* Al = (_Float16*)(sm + 16384);
  float*    Zs = (float*)(sm + 32768);      // [2][32][128] plain

  auto stageA = [&](int buf, int c0) {
#pragma unroll
    for (int i = 0; i < 4; i++) {
      int fid = i * 256 + t;
      int d = fid >> 3, q8 = fid & 7;        // global 8B chunk 0..7
      float4 v = *(const float4*)&W[(size_t)(d0 + d) * CIN + c0 + 4 * q8];
      float* vp = (float*)&v;
      f16x4 h, l;
#pragma unroll
      for (int e = 0; e < 4; e++) {
        _Float16 hh = (_Float16)vp[e];
        h[e] = hh;
        l[e] = (_Float16)(vp[e] - (float)hh);
      }
      int p16 = (q8 >> 1) ^ ((d >> 1) & 3);  // swizzled 16B chunk
      int off = (buf * 128 + d) * 32 + p16 * 8 + (q8 & 1) * 4;
      *(f16x4*)&Ah[off] = h;
      *(f16x4*)&Al[off] = l;
    }
  };
  auto stageZ = [&](int buf, int c0) {
#pragma unroll
    for (int i = 0; i < 4; i++) {
      int r = 8 * w + 2 * i;
      float* lbase = Zs + (size_t)buf * 4096 + r * 128;
      const float* gp = zb + (size_t)(c0 + r + lh) * NN_ + 4 * lr;
      GLDS16(gp, lbase);
    }
  };

  f32x16 acc[2][2];
#pragma unroll
  for (int mt = 0; mt < 2; mt++)
#pragma unroll
    for (int nt = 0; nt < 2; nt++)
#pragma unroll
      for (int i = 0; i < 16; i++) acc[mt][nt][i] = 0.0f;

  stageA(0, 0);
  stageZ(0, 0);
  int buf = 0;
  for (int c0 = 0; c0 < CIN; c0 += 32) {
    __syncthreads();
    if (c0 + 32 < CIN) { stageA(buf ^ 1, c0 + 32); stageZ(buf ^ 1, c0 + 32); }
    const _Float16* AhB = Ah + (size_t)buf * 128 * 32;
    const _Float16* AlB = Al + (size_t)buf * 128 * 32;
    const float*    ZsB = Zs + (size_t)buf * 4096;
#pragma unroll
    for (int s = 0; s < 2; s++) {
      const int cbase = 16 * s + 8 * lh;        // logical c offset (Zs reads)
      const int pa = (2 * s + lh) ^ swz;        // swizzled chunk (A reads)
      const int aoff = pa * 8;
      f16x8 ah0 = *(const f16x8*)&AhB[(wm * 64 + lr) * 32 + aoff];
      f16x8 ah1 = *(const f16x8*)&AhB[(wm * 64 + 32 + lr) * 32 + aoff];
      f16x8 al0 = *(const f16x8*)&AlB[(wm * 64 + lr) * 32 + aoff];
      f16x8 al1 = *(const f16x8*)&AlB[(wm * 64 + 32 + lr) * 32 + aoff];
      f16x8 bh0, bl0, bh1, bl1;
#pragma unroll
      for (int j = 0; j < 8; j++) {
        float x0 = ZsB[(cbase + j) * 128 + wn * 64 + lr];
        float x1 = ZsB[(cbase + j) * 128 + wn * 64 + 32 + lr];
        _Float16 h0 = (_Float16)x0;
        bh0[j] = h0;
        bl0[j] = (_Float16)(x0 - (float)h0);
        _Float16 h1 = (_Float16)x1;
        bh1[j] = h1;
        bl1[j] = (_Float16)(x1 - (float)h1);
      }
      acc[0][0] = MFMA16(ah0, bh0, acc[0][0], 0, 0, 0);
      acc[0][1] = MFMA16(ah0, bh1, acc[0][1], 0, 0, 0);
      acc[1][0] = MFMA16(ah1, bh0, acc[1][0], 0, 0, 0);
      acc[1][1] = MFMA16(ah1, bh1, acc[1][1], 0, 0, 0);
      acc[0][0] = MFMA16(ah0, bl0, acc[0][0], 0, 0, 0);
      acc[0][1] = MFMA16(ah0, bl1, acc[0][1], 0, 0, 0);
      acc[1][0] = MFMA16(ah1, bl0, acc[1][0], 0, 0, 0);
      acc[1][1] = MFMA16(ah1, bl1, acc[1][1], 0, 0, 0);
      acc[0][0] = MFMA16(al0, bh0, acc[0][0], 0, 0, 0);
      acc[0][1] = MFMA16(al0, bh1, acc[0][1], 0, 0, 0);
      acc[1][0] = MFMA16(al1, bh0, acc[1][0], 0, 0, 0);
      acc[1][1] = MFMA16(al1, bh1, acc[1][1], 0, 0, 0);
    }
    buf ^= 1;
  }

  __syncthreads();
  _Float16* Eh = (_Float16*)sm;             // [128][132]
  _Float16* El = (_Float16*)(sm + 33792);
#pragma unroll
  for (int mt = 0; mt < 2; mt++)
#pragma unroll
    for (int nt = 0; nt < 2; nt++) {
      int n_l = wn * 64 + nt * 32 + lr;
#pragma unroll
      for (int g = 0; g < 4; g++) {
        int d_l = wm * 64 + mt * 32 + 8 * g + 4 * lh;
        f16x4 h, l;
#pragma unroll
        for (int e = 0; e < 4; e++) {
          float x = acc[mt][nt][4 * g + e];
          _Float16 hh = (_Float16)x;
          h[e] = hh;
          l[e] = (_Float16)(x - (float)hh);
        }
        *(f16x4*)&Eh[n_l * 132 + d_l] = h;
        *(f16x4*)&El[n_l * 132 + d_l] = l;
      }
    }
  __syncthreads();
  _Float16* gh = zeT_h + ((size_t)b * NN_ + n0) * DD + d0;
  _Float16* gl = zeT_l + ((size_t)b * NN_ + n0) * DD + d0;
#pragma unroll
  for (int i = 0; i < 16; i++) {
    int n = i * 8 + w * 2 + lh;
    int d = 4 * lr;
    *(f16x4*)&gh[(size_t)n * DD + d] = *(const f16x4*)&Eh[n * 132 + d];
    *(f16x4*)&gl[(size_t)n * DD + d] = *(const f16x4*)&El[n * 132 + d];
  }
}

// ---------- kernel 3: MFMA split-f16 partial argmin over one K-split ----------
// LDS rows 64B, 16B chunks XOR-swizzled: phys chunk p of row r holds global
// chunk p ^ ((r>>1)&3)  -> conflict-free b128 fragment reads
__global__ __launch_bounds__(256) void k_argmin(const _Float16* __restrict__ emb_h,
                                                const _Float16* __restrict__ emb_l,
                                                const _Float16* __restrict__ zeT_h,
                                                const _Float16* __restrict__ zeT_l,
                                                const float* __restrict__ esq,
                                                float* __restrict__ pval,
                                                int* __restrict__ pidx) {
  __shared__ __align__(16) char sm[69632];
  const int t = threadIdx.x;
  const int w = t >> 6, lane = t & 63;
  const int lr = lane & 31, lh = lane >> 5;
  const int wm = w & 1, wn = w >> 1;
  const int swz = (lr >> 1) & 3;
  const int b = blockIdx.y, n0 = blockIdx.x * 128, ks = blockIdx.z;
  const int kbase = ks * KPER;

  float* esqs = (float*)(sm + 65536);
  *(float2*)&esqs[2 * t] = *(const float2*)&esq[kbase + 2 * t];

  const _Float16* zb_h = zeT_h + ((size_t)b * NN_ + n0) * DD;
  const _Float16* zb_l = zeT_l + ((size_t)b * NN_ + n0) * DD;

  auto stage = [&](int buf, int kt, int dc) {
    const int k0 = kbase + kt * 128;
    const int q = lane & 3, rr = lane >> 2;
    const int g = q ^ ((rr >> 1) & 3);   // swizzled global 16B chunk for this lane
    const int rb0 = 32 * w;
#pragma unroll
    for (int j = 0; j < 2; j++) {
      int rb = rb0 + 16 * j;
      int r = rb + rr;
      int col = dc + 8 * g;
      size_t eo = (size_t)(k0 + r) * DD + col;
      size_t zo = (size_t)r * DD + col;
      char* lb = sm + (size_t)buf * 8192 + rb * 64;
      GLDS16(emb_h + eo, lb);
      GLDS16(emb_l + eo, lb + 16384);
      GLDS16(zb_h + zo, lb + 32768);
      GLDS16(zb_l + zo, lb + 49152);
    }
  };

  f32x16 vzero;
#pragma unroll
  for (int i = 0; i < 16; i++) vzero[i] = 0.0f;

  float bestv[2];
  int   besti[2];
  bestv[0] = bestv[1] = 3.4e38f;
  besti[0] = besti[1] = 0;

  stage(0, 0, 0);
  int buf = 0;
  for (int kt = 0; kt < 4; kt++) {
    f32x16 acc00 = vzero, acc01 = vzero, acc10 = vzero, acc11 = vzero;
    for (int dc = 0; dc < DD; dc += 32) {
      __syncthreads();
      if (dc + 32 < DD) stage(buf ^ 1, kt, dc + 32);
      else if (kt < 3) stage(buf ^ 1, kt + 1, 0);
      const _Float16* EHb = (const _Float16*)(sm + buf * 8192);
      const _Float16* ELb = (const _Float16*)(sm + 16384 + buf * 8192);
      const _Float16* ZHb = (const _Float16*)(sm + 32768 + buf * 8192);
      const _Float16* ZLb = (const _Float16*)(sm + 49152 + buf * 8192);
#pragma unroll
      for (int s = 0; s < 2; s++) {
        const int p = (2 * s + lh) ^ swz;   // swizzled 16B chunk
        const int acol = p * 8;
        const int ar0 = (wm * 64 + lr) * 32 + acol;
        const int ar1 = (wm * 64 + 32 + lr) * 32 + acol;
        const int br0 = (wn * 64 + lr) * 32 + acol;
        const int br1 = (wn * 64 + 32 + lr) * 32 + acol;
        f16x8 ah0 = *(const f16x8*)(EHb + ar0);
        f16x8 ah1 = *(const f16x8*)(EHb + ar1);
        f16x8 al0 = *(const f16x8*)(ELb + ar0);
        f16x8 al1 = *(const f16x8*)(ELb + ar1);
        f16x8 bh0 = *(const f16x8*)(ZHb + br0);
        f16x8 bh1 = *(const f16x8*)(ZHb + br1);
        f16x8 bl0 = *(const f16x8*)(ZLb + br0);
        f16x8 bl1 = *(const f16x8*)(ZLb + br1);
        acc00 = MFMA16(ah0, bh0, acc00, 0, 0, 0);
        acc01 = MFMA16(ah0, bh1, acc01, 0, 0, 0);
        acc10 = MFMA16(ah1, bh0, acc10, 0, 0, 0);
        acc11 = MFMA16(ah1, bh1, acc11, 0, 0, 0);
        acc00 = MFMA16(ah0, bl0, acc00, 0, 0, 0);
        acc01 = MFMA16(ah0, bl1, acc01, 0, 0, 0);
        acc10 = MFMA16(ah1, bl0, acc10, 0, 0, 0);
        acc11 = MFMA16(ah1, bl1, acc11, 0, 0, 0);
        acc00 = MFMA16(al0, bh0, acc00, 0, 0, 0);
        acc01 = MFMA16(al0, bh1, acc01, 0, 0, 0);
        acc10 = MFMA16(al1, bh0, acc10, 0, 0, 0);
        acc11 = MFMA16(al1, bh1, acc11, 0, 0, 0);
      }
      buf ^= 1;
    }
#pragma unroll
    for (int mt = 0; mt < 2; mt++)
#pragma unroll
      for (int nt = 0; nt < 2; nt++) {
        const f32x16& a = (mt == 0) ? (nt == 0 ? acc00 : acc01)
                                    : (nt == 0 ? acc10 : acc11);
#pragma unroll
        for (int r = 0; r < 16; r++) {
          int kl = kt * 128 + wm * 64 + mt * 32 + (r & 3) + 8 * (r >> 2) + 4 * lh;
          float d2 = esqs[kl] - 2.0f * a[r];
          int kg = kbase + kl;
          if (d2 < bestv[nt] || (d2 == bestv[nt] && kg < besti[nt])) {
            bestv[nt] = d2; besti[nt] = kg;
          }
        }
      }
  }

#pragma unroll
  for (int nt = 0; nt < 2; nt++) {
    float ov = __shfl_xor(bestv[nt], 32, 64);
    int   oi = __shfl_xor(besti[nt], 32, 64);
    if (ov < bestv[nt] || (ov == bestv[nt] && oi < besti[nt])) {
      bestv[nt] = ov; besti[nt] = oi;
    }
  }
  float* pv = (float*)(sm + 67584);
  int*   pi = (int*)(sm + 68608);
  __syncthreads();
  if (lh == 0) {
#pragma unroll
    for (int nt = 0; nt < 2; nt++) {
      pv[(w * 2 + nt) * 32 + lr] = bestv[nt];
      pi[(w * 2 + nt) * 32 + lr] = besti[nt];
    }
  }
  __syncthreads();
  if (t < 128) {
    int wn2 = t >> 6, nt = (t >> 5) & 1, nl = t & 31;
    int i0 = ((2 * wn2 + 0) * 2 + nt) * 32 + nl;
    int i1 = ((2 * wn2 + 1) * 2 + nt) * 32 + nl;
    float v0 = pv[i0], v1 = pv[i1];
    int   j0 = pi[i0], j1 = pi[i1];
    if (v1 < v0 || (v1 == v0 && j1 < j0)) { v0 = v1; j0 = j1; }
    size_t o = ((size_t)ks * B_ + b) * NN_ + n0 + t;
    pval[o] = v0;
    pidx[o] = j0;
  }
}

// ---------- kernel 4: merge K-split partials -> mind ; histogram -> hist ----------
__global__ __launch_bounds__(256) void k_histm(const float* __restrict__ pval,
                                               const int* __restrict__ pidx,
                                               int* __restrict__ mind,
                                               int* __restrict__ hist) {
  __shared__ int h[KK];
  const int t = threadIdx.x;
#pragma unroll
  for (int i = 0; i < 8; i++) h[t + 256 * i] = 0;
  __syncthreads();
  const int base = blockIdx.x * 2048;
#pragma unroll
  for (int i = 0; i < 8; i++) {
    int g = base + i * 256 + t;
    float bv = pval[g];
    int   bi = pidx[g];
#pragma unroll
    for (int ks = 1; ks < KSPLIT; ks++) {
      float v = pval[(size_t)ks * NG + g];
      int  ii = pidx[(size_t)ks * NG + g];
      if (v < bv || (v == bv && ii < bi)) { bv = v; bi = ii; }
    }
    mind[g] = bi;
    atomicAdd(&h[bi], 1);
  }
  __syncthreads();
#pragma unroll
  for (int i = 0; i < 8; i++) {
    int v = h[t + 256 * i];
    if (v) atomicAdd(&hist[t + 256 * i], v);
  }
}

// ---------- kernel 5: exclusive prefix sum of hist -> cursor ; n_sum floats ----------
__global__ __launch_bounds__(256) void k_scan(const int* __restrict__ hist,
                                              int* __restrict__ cursor,
                                              float* __restrict__ nsumf) {
  __shared__ int ps[256];
  const int t = threadIdx.x;
  int c[8], s = 0;
#pragma unroll
  for (int e = 0; e < 8; e++) { c[e] = hist[8 * t + e]; s += c[e]; }
  ps[t] = s;
  __syncthreads();
  for (int off = 1; off < 256; off <<= 1) {
    int v = (t >= off) ? ps[t - off] : 0;
    __syncthreads();
    ps[t] += v;
    __syncthreads();
  }
  int run = ps[t] - s;
#pragma unroll
  for (int e = 0; e < 8; e++) {
    cursor[8 * t + e] = run;
    nsumf[8 * t + e] = (float)c[e];
    run += c[e];
  }
}

// ---------- kernel 6: scatter sample ids into sorted order (packed k<<15|g) ----------
__global__ __launch_bounds__(256) void k_pos(const int* __restrict__ mind,
                                             int* __restrict__ cursor,
                                             int* __restrict__ sortp) {
  int g = blockIdx.x * 256 + threadIdx.x;
  int k = mind[g];
  int p = atomicAdd(&cursor[k], 1);
  sortp[p] = (k << 15) | g;
}

// ---------- kernel 7: out[b,d,n] = emb[mind[b,n], d] ----------
__global__ __launch_bounds__(256) void k_out(const float* __restrict__ emb,
                                             const int* __restrict__ mind,
                                             float* __restrict__ out) {
  __shared__ __align__(16) float E[64][257];
  __shared__ int idxl[64];
  const int t = threadIdx.x;
  const int b  = blockIdx.y;
  const int n0 = blockIdx.x * 64;
  if (t < 64) idxl[t] = mind[(size_t)b * NN_ + n0 + t];
  __syncthreads();

  for (int i = 0; i < 16; i++) {
    int cid = t + 256 * i;
    int r = cid >> 6, q = cid & 63;
    float4 v = *(const float4*)&emb[(size_t)idxl[r] * DD + 4 * q];
    float* vp = (float*)&v;
    E[r][4 * q + 0] = vp[0];
    E[r][4 * q + 1] = vp[1];
    E[r][4 * q + 2] = vp[2];
    E[r][4 * q + 3] = vp[3];
  }
  __syncthreads();
  const int nq = t & 15, dg = t >> 4;
  float* outb = out + (size_t)b * DD * NN_ + n0;
#pragma unroll
  for (int i = 0; i < 16; i++) {
    int d = i * 16 + dg;
    float4 v = make_float4(E[4 * nq + 0][d], E[4 * nq + 1][d],
                           E[4 * nq + 2][d], E[4 * nq + 3][d]);
    *(float4*)&outb[(size_t)d * NN_ + 4 * nq] = v;
  }
}

// ---------- kernel 8: segment-sum over sorted runs -> z_sum ----------
__global__ __launch_bounds__(256) void k_zsum(const int* __restrict__ sortp,
                                              const _Float16* __restrict__ zeT_h,
                                              const _Float16* __restrict__ zeT_l,
                                              float* __restrict__ z_sum) {
  __shared__ int sg[256];
  const int t = threadIdx.x;
  const int w = t >> 6, lane = t & 63;
  sg[t] = sortp[blockIdx.x * 256 + t];
  __syncthreads();
  const int base = w * 64;
  float acc[4] = {0.f, 0.f, 0.f, 0.f};
  int cur = sg[base] >> 15;
  for (int j = 0; j < 64; j++) {
    int e = sg[base + j];
    int k = e >> 15, g = e & 32767;
    if (k != cur) {
      float* zs = &z_sum[(size_t)cur * DD + 4 * lane];
#pragma unroll
      for (int x = 0; x < 4; x++) { atomicAdd(&zs[x], acc[x]); acc[x] = 0.f; }
      cur = k;
    }
    f16x4 h = *(const f16x4*)&zeT_h[(size_t)g * DD + 4 * lane];
    f16x4 l = *(const f16x4*)&zeT_l[(size_t)g * DD + 4 * lane];
#pragma unroll
    for (int x = 0; x < 4; x++) acc[x] += (float)h[x] + (float)l[x];
  }
  float* zs = &z_sum[(size_t)cur * DD + 4 * lane];
#pragma unroll
  for (int x = 0; x < 4; x++) atomicAdd(&zs[x], acc[x]);
}

// ---------- kernel 9: EMA update ----------
__global__ __launch_bounds__(256) void k_ema(const float* __restrict__ ema_numer,
                                             const float* __restrict__ ema_denom,
                                             const float* __restrict__ z_sum,
                                             const float* __restrict__ nsumf,
                                             float* __restrict__ out_numer,
                                             float* __restrict__ out_denom) {
  const float G  = 0.99f;
  const float OG = 0.009999999776482582f;
  int i = blockIdx.x * 256 + threadIdx.x;
  if (i < KK * DD) {
    out_numer[i] = G * ema_numer[i] + OG * z_sum[i];
  } else {
    int j = i - KK * DD;
    if (j < KK) out_denom[j] = G * ema_denom[j] + OG * nsumf[j];
  }
}

extern "C" void kernel_launch(void* const* d_in, const int* in_sizes, int n_in,
                              void* d_out, int out_size, void* d_ws, size_t ws_size,
                              hipStream_t stream) {
  (void)in_sizes; (void)n_in; (void)out_size; (void)ws_size;
  const float* z         = (const float*)d_in[0];
  const float* W         = (const float*)d_in[1];
  const float* emb       = (const float*)d_in[2];
  const float* ema_numer = (const float*)d_in[3];
  const float* ema_denom = (const float*)d_in[4];

  float* out       = (float*)d_out;                        // (8,256,4096)
  float* out_numer = out + (size_t)B_ * DD * NN_;
  float* out_denom = out_numer + (size_t)KK * DD;

  const size_t ZET = (size_t)B_ * NN_ * DD;                // 8388608
  _Float16* zeT_h = (_Float16*)d_ws;                       // 16 MB
  _Float16* zeT_l = zeT_h + ZET;                           // 16 MB
  float* esq    = (float*)(zeT_l + ZET);                   // 2048
  float* zsum   = esq + KK;                                // 524288 (memset)
  int*   hist   = (int*)(zsum + (size_t)KK * DD);          // 2048   (memset, contiguous)
  int*   cursor = hist + KK;                               // 2048
  float* nsumf  = (float*)(cursor + KK);                   // 2048
  float* pval   = nsumf + KK;                              // 131072
  int*   pidx   = (int*)(pval + (size_t)KSPLIT * NG);      // 131072
  int*   mind   = pidx + (size_t)KSPLIT * NG;              // 32768
  int*   sortp  = mind + NG;                               // 32768
  _Float16* emb_h = (_Float16*)(sortp + NG);               // 524288 f16
  _Float16* emb_l = emb_h + (size_t)KK * DD;               // 524288 f16

  hipMemsetAsync(zsum, 0, (size_t)(KK * DD + KK) * sizeof(float), stream);

  k_esq<<<dim3(KK / 4), 256, 0, stream>>>(emb, esq, emb_h, emb_l);
  k_ze<<<dim3(NN_ / 128, DD / 128, B_), 256, 0, stream>>>(W, z, zeT_h, zeT_l);
  k_argmin<<<dim3(NN_ / 128, B_, KSPLIT), 256, 0, stream>>>(emb_h, emb_l, zeT_h, zeT_l,
                                                            esq, pval, pidx);
  k_histm<<<dim3(NG / 2048), 256, 0, stream>>>(pval, pidx, mind, hist);
  k_scan<<<dim3(1), 256, 0, stream>>>(hist, cursor, nsumf);
  k_pos<<<dim3(NG / 256), 256, 0, stream>>>(mind, cursor, sortp);
  k_out<<<dim3(NN_ / 64, B_), 256, 0, stream>>>(emb, mind, out);
  k_zsum<<<dim3(NG / 256), 256, 0, stream>>>(sortp, zeT_h, zeT_l, zsum);
  k_ema<<<dim3((KK * DD + KK) / 256), 256, 0, stream>>>(ema_numer, ema_denom, zsum, nsumf,
                                                        out_numer, out_denom);
}